// Round 1
// baseline (1982.726 us; speedup 1.0000x reference)
//
#include <hip/hip_runtime.h>
#include <hip/hip_bf16.h>

#define DEV __device__ __forceinline__

typedef __attribute__((ext_vector_type(8))) short bf16x8;
typedef __attribute__((ext_vector_type(4))) float f32x4;

constexpr int B_ = 2, S_ = 2048, HID_ = 4096, NH_ = 32, NKV_ = 8, D_ = 128;
constexpr int GROUPS_ = NH_ / NKV_;

DEV unsigned short f2bf(float x) {
    union { float f; unsigned int u; } v; v.f = x;
    unsigned int r = v.u + 0x7fffu + ((v.u >> 16) & 1u);
    return (unsigned short)(r >> 16);
}

DEV f32x4 mfma16(bf16x8 a, bf16x8 b, f32x4 c) {
    return __builtin_amdgcn_mfma_f32_16x16x32_bf16(a, b, c, 0, 0, 0);
}

// C = A @ B^T.  A: M x K (f32 or bf16 row-major), B: N x K (f32 row-major).
// EPI 0: f32 row-major store. EPI 1: RoPE + bf16 row-major store (N must be
// multiple of 128, head dim 128). EPI 3: bf16 transposed V store (B,NKV,D,S).
template<int EPI, bool ABF16>
__global__ __launch_bounds__(256) void gemm_bt_k(
    const void* __restrict__ Ap, const float* __restrict__ Bp,
    void* __restrict__ Cp, const float* __restrict__ cosT,
    const float* __restrict__ sinT, int M, int N, int K)
{
    constexpr int LDT = 40;  // LDS row stride in bf16 (80B: 16B-aligned, bank-spread)
    __shared__ __align__(16) unsigned short Asm[128 * LDT];
    __shared__ __align__(16) unsigned short Bsm[128 * LDT];
    const int tid = threadIdx.x;
    const int lane = tid & 63;
    const int w = tid >> 6;
    const int la = lane & 15, lb = lane >> 4;
    const int ntn = N >> 7;
    const int bm = (int)(blockIdx.x / ntn) << 7;
    const int bn = (int)(blockIdx.x % ntn) << 7;

    f32x4 acc[2][8];
#pragma unroll
    for (int i = 0; i < 2; ++i)
#pragma unroll
        for (int j = 0; j < 8; ++j) acc[i][j] = f32x4{0.f, 0.f, 0.f, 0.f};

    for (int kt = 0; kt < K; kt += 32) {
        // ---- stage A tile (128 x 32) into LDS as bf16 ----
        if constexpr (!ABF16) {
#pragma unroll
            for (int it = 0; it < 4; ++it) {
                int idx = it * 256 + tid;
                int r = idx >> 3, c = (idx & 7) << 2;
                const float* g = (const float*)Ap + (size_t)(bm + r) * K + kt + c;
                f32x4 v = *(const f32x4*)g;
                union { unsigned long long q; unsigned short u[4]; } pk;
                pk.u[0] = f2bf(v[0]); pk.u[1] = f2bf(v[1]);
                pk.u[2] = f2bf(v[2]); pk.u[3] = f2bf(v[3]);
                *(unsigned long long*)&Asm[r * LDT + c] = pk.q;
            }
        } else {
#pragma unroll
            for (int it = 0; it < 2; ++it) {
                int idx = it * 256 + tid;
                int r = idx >> 2, c = (idx & 3) << 3;
                const unsigned short* g =
                    (const unsigned short*)Ap + (size_t)(bm + r) * K + kt + c;
                *(bf16x8*)&Asm[r * LDT + c] = *(const bf16x8*)g;
            }
        }
        // ---- stage B tile (128 x 32) into LDS as bf16 ----
#pragma unroll
        for (int it = 0; it < 4; ++it) {
            int idx = it * 256 + tid;
            int r = idx >> 3, c = (idx & 7) << 2;
            const float* g = Bp + (size_t)(bn + r) * K + kt + c;
            f32x4 v = *(const f32x4*)g;
            union { unsigned long long q; unsigned short u[4]; } pk;
            pk.u[0] = f2bf(v[0]); pk.u[1] = f2bf(v[1]);
            pk.u[2] = f2bf(v[2]); pk.u[3] = f2bf(v[3]);
            *(unsigned long long*)&Bsm[r * LDT + c] = pk.q;
        }
        __syncthreads();

        // ---- MFMA: wave w owns rows [w*32, w*32+32), all 128 cols ----
        bf16x8 af0 = *(bf16x8*)&Asm[(w * 32 + la) * LDT + lb * 8];
        bf16x8 af1 = *(bf16x8*)&Asm[(w * 32 + 16 + la) * LDT + lb * 8];
#pragma unroll
        for (int nb = 0; nb < 8; ++nb) {
            bf16x8 bfr = *(bf16x8*)&Bsm[(nb * 16 + la) * LDT + lb * 8];
            acc[0][nb] = mfma16(af0, bfr, acc[0][nb]);
            acc[1][nb] = mfma16(af1, bfr, acc[1][nb]);
        }
        __syncthreads();
    }

    const int rbase = bm + w * 32;
    if constexpr (EPI == 0) {
        float* C = (float*)Cp;
#pragma unroll
        for (int mf = 0; mf < 2; ++mf)
#pragma unroll
            for (int nb = 0; nb < 8; ++nb)
#pragma unroll
                for (int r = 0; r < 4; ++r)
                    C[(size_t)(rbase + mf * 16 + lb * 4 + r) * N + bn + nb * 16 + la] =
                        acc[mf][nb][r];
    } else if constexpr (EPI == 1) {
        // RoPE: cols within a 128-aligned tile are one head; pair (d, d+64).
        unsigned short* C = (unsigned short*)Cp;
#pragma unroll
        for (int mf = 0; mf < 2; ++mf) {
#pragma unroll
            for (int r = 0; r < 4; ++r) {
                int m = rbase + mf * 16 + lb * 4 + r;  // m = b*S + s
                const float* cb = cosT + (size_t)m * D_;
                const float* sb = sinT + (size_t)m * D_;
#pragma unroll
                for (int nb = 0; nb < 4; ++nb) {
                    int d = nb * 16 + la;  // d < 64
                    float c = cb[d], s = sb[d];
                    float x1 = acc[mf][nb][r], x2 = acc[mf][nb + 4][r];
                    C[(size_t)m * N + bn + d]      = f2bf(x1 * c - x2 * s);
                    C[(size_t)m * N + bn + d + 64] = f2bf(x2 * c + x1 * s);
                }
            }
        }
    } else {  // EPI == 3: V^T  (B, NKV, D, S)
        unsigned short* C = (unsigned short*)Cp;
#pragma unroll
        for (int mf = 0; mf < 2; ++mf)
#pragma unroll
            for (int nb = 0; nb < 8; ++nb)
#pragma unroll
                for (int r = 0; r < 4; ++r) {
                    int m = rbase + mf * 16 + lb * 4 + r;
                    int b = m >> 11, s = m & (S_ - 1);
                    int n = bn + nb * 16 + la;
                    int kv = n >> 7, d = n & 127;
                    C[(((size_t)b * NKV_ + kv) * D_ + d) * S_ + s] =
                        f2bf(acc[mf][nb][r]);
                }
    }
}

// Flash attention, causal, GQA. Q: (B,S,NH,D) bf16, K: (B,S,NKV,D) bf16,
// Vt: (B,NKV,D,S) bf16, Ow: (B,S,NH*D) bf16. 4 waves/block, 16 q-rows/wave.
__global__ __launch_bounds__(256) void attn_k(
    const unsigned short* __restrict__ Qw, const unsigned short* __restrict__ Kw,
    const unsigned short* __restrict__ Vt, unsigned short* __restrict__ Ow)
{
    __shared__ __align__(16) unsigned short Pl[4][16 * 40];
    const int tid = threadIdx.x, lane = tid & 63, w = tid >> 6;
    const int la = lane & 15, lb = lane >> 4;
    constexpr int nqb = S_ / 64;
    const int blk = blockIdx.x;
    const int b = blk / (NH_ * nqb);
    const int rem = blk % (NH_ * nqb);
    const int h = rem / nqb;
    const int qb = (rem % nqb) * 64;
    const int kvh = h / GROUPS_;
    const int qbase = qb + w * 16;
    const float scale = 0.08838834764831845f;  // 1/sqrt(128)

    // Q fragments for this wave's 16 rows (kept in registers for all KV tiles)
    bf16x8 qf[4];
    const unsigned short* qptr =
        Qw + ((size_t)(b * S_ + qbase + la) * NH_ + h) * D_ + lb * 8;
#pragma unroll
    for (int kc = 0; kc < 4; ++kc) qf[kc] = *(const bf16x8*)(qptr + kc * 32);

    float mrow[4], lrow[4];
    f32x4 oacc[8];
#pragma unroll
    for (int r = 0; r < 4; ++r) { mrow[r] = -INFINITY; lrow[r] = 0.f; }
#pragma unroll
    for (int db = 0; db < 8; ++db) oacc[db] = f32x4{0.f, 0.f, 0.f, 0.f};

    const int ntiles = (qbase + 16 + 31) / 32;
    for (int kt = 0; kt < ntiles; ++kt) {
        const int kv0 = kt * 32;
        f32x4 sacc[2];
        sacc[0] = f32x4{0.f, 0.f, 0.f, 0.f};
        sacc[1] = f32x4{0.f, 0.f, 0.f, 0.f};
        const unsigned short* kbase =
            Kw + ((size_t)(b * S_ + kv0) * NKV_ + kvh) * D_;
#pragma unroll
        for (int kc = 0; kc < 4; ++kc) {
            bf16x8 kf0 = *(const bf16x8*)(kbase + (size_t)la * NKV_ * D_ + kc * 32 + lb * 8);
            bf16x8 kf1 = *(const bf16x8*)(kbase + (size_t)(la + 16) * NKV_ * D_ + kc * 32 + lb * 8);
            sacc[0] = mfma16(qf[kc], kf0, sacc[0]);
            sacc[1] = mfma16(qf[kc], kf1, sacc[1]);
        }
        // online softmax (rows = (lb*4+r), cols = kv0 + nb*16 + la)
        const int qrow0 = qbase + lb * 4;
        float sv[2][4];
#pragma unroll
        for (int nb = 0; nb < 2; ++nb) {
            int kvc = kv0 + nb * 16 + la;
#pragma unroll
            for (int r = 0; r < 4; ++r) {
                float s = sacc[nb][r] * scale;
                sv[nb][r] = (kvc > qrow0 + r) ? -INFINITY : s;
            }
        }
        float tmax[4], tsum[4], fac[4];
#pragma unroll
        for (int r = 0; r < 4; ++r) tmax[r] = fmaxf(sv[0][r], sv[1][r]);
#pragma unroll
        for (int d = 1; d < 16; d <<= 1)
#pragma unroll
            for (int r = 0; r < 4; ++r)
                tmax[r] = fmaxf(tmax[r], __shfl_xor(tmax[r], d));
#pragma unroll
        for (int r = 0; r < 4; ++r) {
            float mn = fmaxf(mrow[r], tmax[r]);
            fac[r] = __expf(mrow[r] - mn);
            mrow[r] = mn;
        }
#pragma unroll
        for (int nb = 0; nb < 2; ++nb)
#pragma unroll
            for (int r = 0; r < 4; ++r)
                sv[nb][r] = __expf(sv[nb][r] - mrow[r]);
#pragma unroll
        for (int r = 0; r < 4; ++r) tsum[r] = sv[0][r] + sv[1][r];
#pragma unroll
        for (int d = 1; d < 16; d <<= 1)
#pragma unroll
            for (int r = 0; r < 4; ++r) tsum[r] += __shfl_xor(tsum[r], d);
#pragma unroll
        for (int r = 0; r < 4; ++r) lrow[r] = lrow[r] * fac[r] + tsum[r];
#pragma unroll
        for (int db = 0; db < 8; ++db)
#pragma unroll
            for (int r = 0; r < 4; ++r) oacc[db][r] *= fac[r];

        // P (16x32) -> LDS (per-wave region), reread in A-fragment layout
        unsigned short* pl = &Pl[w][0];
#pragma unroll
        for (int nb = 0; nb < 2; ++nb)
#pragma unroll
            for (int r = 0; r < 4; ++r)
                pl[(lb * 4 + r) * 40 + nb * 16 + la] = f2bf(sv[nb][r]);
        bf16x8 pa = *(bf16x8*)&pl[la * 40 + lb * 8];

        // O += P @ V   (V^T rows are K-contiguous)
        const unsigned short* vbase =
            Vt + (size_t)(b * NKV_ + kvh) * D_ * S_ + kv0 + lb * 8;
#pragma unroll
        for (int db = 0; db < 8; ++db) {
            bf16x8 vf = *(const bf16x8*)(vbase + (size_t)(db * 16 + la) * S_);
            oacc[db] = mfma16(pa, vf, oacc[db]);
        }
    }

    // normalize + store (B,S,NH*D) bf16
#pragma unroll
    for (int db = 0; db < 8; ++db)
#pragma unroll
        for (int r = 0; r < 4; ++r) {
            int qrow = qbase + lb * 4 + r;
            float v = oacc[db][r] / lrow[r];
            Ow[(size_t)(b * S_ + qrow) * (NH_ * D_) + h * D_ + db * 16 + la] = f2bf(v);
        }
}

extern "C" void kernel_launch(void* const* d_in, const int* in_sizes, int n_in,
                              void* d_out, int out_size, void* d_ws, size_t ws_size,
                              hipStream_t stream) {
    const float* hs   = (const float*)d_in[0];
    const float* cosT = (const float*)d_in[1];
    const float* sinT = (const float*)d_in[2];
    const float* Wq   = (const float*)d_in[3];
    const float* Wk   = (const float*)d_in[4];
    const float* Wv   = (const float*)d_in[5];
    const float* Wo   = (const float*)d_in[6];

    unsigned short* Qws  = (unsigned short*)d_ws;
    unsigned short* Kws  = Qws + (size_t)B_ * S_ * NH_ * D_;
    unsigned short* Vtws = Kws + (size_t)B_ * S_ * NKV_ * D_;
    unsigned short* AOws = Vtws + (size_t)B_ * S_ * NKV_ * D_;

    const int M = B_ * S_;
    dim3 blk(256);
    // Q = rope(H @ Wq^T)
    gemm_bt_k<1, false><<<dim3((M / 128) * (NH_ * D_ / 128)), blk, 0, stream>>>(
        hs, Wq, Qws, cosT, sinT, M, NH_ * D_, HID_);
    // K = rope(H @ Wk^T)
    gemm_bt_k<1, false><<<dim3((M / 128) * (NKV_ * D_ / 128)), blk, 0, stream>>>(
        hs, Wk, Kws, cosT, sinT, M, NKV_ * D_, HID_);
    // V^T = (H @ Wv^T)^T
    gemm_bt_k<3, false><<<dim3((M / 128) * (NKV_ * D_ / 128)), blk, 0, stream>>>(
        hs, Wv, Vtws, nullptr, nullptr, M, NKV_ * D_, HID_);
    // attention
    attn_k<<<dim3(B_ * NH_ * (S_ / 64)), blk, 0, stream>>>(Qws, Kws, Vtws, AOws);
    // out = AO @ Wo^T
    gemm_bt_k<0, true><<<dim3((M / 128) * (HID_ / 128)), blk, 0, stream>>>(
        AOws, Wo, (float*)d_out, nullptr, nullptr, M, HID_, NH_ * D_);
}

// Round 2
// 782.537 us; speedup vs baseline: 2.5337x; 2.5337x over previous
//
#include <hip/hip_runtime.h>
#include <hip/hip_bf16.h>

#define DEV __device__ __forceinline__

typedef __attribute__((ext_vector_type(8))) short bf16x8;
typedef __attribute__((ext_vector_type(4))) short s16x4;
typedef __attribute__((ext_vector_type(4))) float f32x4;

constexpr int B_ = 2, S_ = 2048, HID_ = 4096, NH_ = 32, NKV_ = 8, D_ = 128;
constexpr int GROUPS_ = NH_ / NKV_;
// fold 1/sqrt(D) and log2(e) into Q so attention uses exp2 directly
constexpr float QSCALE_ = 0.08838834764831845f * 1.4426950408889634f;

DEV unsigned short f2bf(float x) {
    union { float f; unsigned int u; } v; v.f = x;
    unsigned int r = v.u + 0x7fffu + ((v.u >> 16) & 1u);
    return (unsigned short)(r >> 16);
}

DEV f32x4 mfma16(bf16x8 a, bf16x8 b, f32x4 c) {
    return __builtin_amdgcn_mfma_f32_16x16x32_bf16(a, b, c, 0, 0, 0);
}

DEV void gll16(const void* g, void* l) {
    __builtin_amdgcn_global_load_lds(
        (const __attribute__((address_space(1))) unsigned int*)g,
        (__attribute__((address_space(3))) unsigned int*)l, 16, 0, 0);
}

// ---------------- fp32 -> bf16 cast (vectorized, memory-bound) ----------------
__global__ __launch_bounds__(256) void cast_bf16_k(
    const float* __restrict__ src, unsigned short* __restrict__ dst, int n8)
{
    int i = blockIdx.x * 256 + threadIdx.x;
    if (i >= n8) return;
    const f32x4* s = (const f32x4*)(src + (size_t)i * 8);
    f32x4 a = s[0], b = s[1];
    bf16x8 o;
    o[0] = (short)f2bf(a[0]); o[1] = (short)f2bf(a[1]);
    o[2] = (short)f2bf(a[2]); o[3] = (short)f2bf(a[3]);
    o[4] = (short)f2bf(b[0]); o[5] = (short)f2bf(b[1]);
    o[6] = (short)f2bf(b[2]); o[7] = (short)f2bf(b[3]);
    *(bf16x8*)(dst + (size_t)i * 8) = o;
}

// ---------------- bf16 GEMM, m97 structure: 128x128 tile, BK=32 ---------------
// C = A @ B^T. A: MxK bf16 row-major, B: NxK bf16 row-major.
// WSPLIT 0: waves 2x2 (64x64/wave, acc[4][4]).  WSPLIT 1: waves 4x1 (32x128, acc[2][8]).
// EPI 0: f32 row-major. EPI 1: RoPE*scale -> bf16 row-major (head dim 128 tiles).
// EPI 3: bf16 transposed V store (B,NKV,D,S).
template<int EPI, int WSPLIT>
__global__ __launch_bounds__(256) void gemm_bf16_k(
    const unsigned short* __restrict__ A, const unsigned short* __restrict__ Bw,
    void* __restrict__ Cp, const float* __restrict__ cosT,
    const float* __restrict__ sinT, int M, int N, int K, float scale)
{
    __shared__ __align__(16) unsigned short Asm[128 * 32];
    __shared__ __align__(16) unsigned short Bsm[128 * 32];
    const int tid = threadIdx.x, lane = tid & 63, w = tid >> 6;
    const int la = lane & 15, lb = lane >> 4;
    const int ntn = N >> 7;
    const int bm = (int)(blockIdx.x / ntn) << 7;
    const int bn = (int)(blockIdx.x % ntn) << 7;

    constexpr int NACM = WSPLIT ? 2 : 4;
    constexpr int NACN = WSPLIT ? 8 : 4;
    f32x4 acc[NACM][NACN];
#pragma unroll
    for (int i = 0; i < NACM; ++i)
#pragma unroll
        for (int j = 0; j < NACN; ++j) acc[i][j] = f32x4{0.f, 0.f, 0.f, 0.f};

    const int r0 = tid >> 2, c0 = (tid & 3) << 3;
    const unsigned short* ga = A + (size_t)(bm + r0) * K + c0;
    const unsigned short* gb = Bw + (size_t)(bn + r0) * K + c0;
    const int arow = WSPLIT ? (w * 32) : ((w >> 1) * 64);
    const int brow = WSPLIT ? 0 : ((w & 1) * 64);

    for (int kt = 0; kt < K; kt += 32) {
        // stage A/B tiles (128x32 bf16 = 8KB each) direct global->LDS, 16B/lane
        gll16(ga + kt, &Asm[tid * 8]);
        gll16(ga + (size_t)64 * K + kt, &Asm[2048 + tid * 8]);
        gll16(gb + kt, &Bsm[tid * 8]);
        gll16(gb + (size_t)64 * K + kt, &Bsm[2048 + tid * 8]);
        __syncthreads();

        bf16x8 af[NACM], bf[NACN];
#pragma unroll
        for (int mi = 0; mi < NACM; ++mi)
            af[mi] = *(const bf16x8*)&Asm[(arow + mi * 16 + la) * 32 + lb * 8];
#pragma unroll
        for (int ni = 0; ni < NACN; ++ni)
            bf[ni] = *(const bf16x8*)&Bsm[(brow + ni * 16 + la) * 32 + lb * 8];
#pragma unroll
        for (int mi = 0; mi < NACM; ++mi)
#pragma unroll
            for (int ni = 0; ni < NACN; ++ni)
                acc[mi][ni] = mfma16(af[mi], bf[ni], acc[mi][ni]);
        __syncthreads();
    }

    if constexpr (EPI == 0) {
        float* C = (float*)Cp;
        const int rb = bm + ((w >> 1) * 64), cb = bn + ((w & 1) * 64);
#pragma unroll
        for (int mi = 0; mi < NACM; ++mi)
#pragma unroll
            for (int ni = 0; ni < NACN; ++ni)
#pragma unroll
                for (int r = 0; r < 4; ++r)
                    C[(size_t)(rb + mi * 16 + lb * 4 + r) * N + cb + ni * 16 + la] =
                        acc[mi][ni][r];
    } else if constexpr (EPI == 1) {
        unsigned short* C = (unsigned short*)Cp;
        const int rbase = bm + w * 32;
#pragma unroll
        for (int mf = 0; mf < 2; ++mf) {
#pragma unroll
            for (int r = 0; r < 4; ++r) {
                int m = rbase + mf * 16 + lb * 4 + r;  // m = b*S + s
                const float* cb = cosT + (size_t)m * D_;
                const float* sb = sinT + (size_t)m * D_;
#pragma unroll
                for (int nb = 0; nb < 4; ++nb) {
                    int d = nb * 16 + la;  // d < 64; cos[d]==cos[d+64]
                    float c = cb[d], s = sb[d];
                    float x1 = acc[mf][nb][r], x2 = acc[mf][nb + 4][r];
                    C[(size_t)m * N + bn + d]      = f2bf((x1 * c - x2 * s) * scale);
                    C[(size_t)m * N + bn + d + 64] = f2bf((x2 * c + x1 * s) * scale);
                }
            }
        }
    } else {  // EPI == 3: V^T (B,NKV,D,S)
        unsigned short* C = (unsigned short*)Cp;
        const int rbase = bm + w * 32;
#pragma unroll
        for (int mf = 0; mf < 2; ++mf)
#pragma unroll
            for (int nb = 0; nb < NACN; ++nb)
#pragma unroll
                for (int r = 0; r < 4; ++r) {
                    int m = rbase + mf * 16 + lb * 4 + r;
                    int b = m >> 11, s = m & (S_ - 1);
                    int n = bn + nb * 16 + la;
                    int kv = n >> 7, d = n & 127;
                    C[(((size_t)b * NKV_ + kv) * D_ + d) * S_ + s] =
                        f2bf(acc[mf][nb][r]);
                }
    }
}

// ---------------- legacy fp32-input GEMM (round-1 structure, ws fallback) -----
template<int EPI, bool ABF16>
__global__ __launch_bounds__(256) void gemm_legacy_k(
    const void* __restrict__ Ap, const float* __restrict__ Bp,
    void* __restrict__ Cp, const float* __restrict__ cosT,
    const float* __restrict__ sinT, int M, int N, int K, float scale)
{
    constexpr int LDT = 40;
    __shared__ __align__(16) unsigned short Asm[128 * LDT];
    __shared__ __align__(16) unsigned short Bsm[128 * LDT];
    const int tid = threadIdx.x;
    const int lane = tid & 63;
    const int w = tid >> 6;
    const int la = lane & 15, lb = lane >> 4;
    const int ntn = N >> 7;
    const int bm = (int)(blockIdx.x / ntn) << 7;
    const int bn = (int)(blockIdx.x % ntn) << 7;

    f32x4 acc[2][8];
#pragma unroll
    for (int i = 0; i < 2; ++i)
#pragma unroll
        for (int j = 0; j < 8; ++j) acc[i][j] = f32x4{0.f, 0.f, 0.f, 0.f};

    for (int kt = 0; kt < K; kt += 32) {
        if constexpr (!ABF16) {
#pragma unroll
            for (int it = 0; it < 4; ++it) {
                int idx = it * 256 + tid;
                int r = idx >> 3, c = (idx & 7) << 2;
                const float* g = (const float*)Ap + (size_t)(bm + r) * K + kt + c;
                f32x4 v = *(const f32x4*)g;
                union { unsigned long long q; unsigned short u[4]; } pk;
                pk.u[0] = f2bf(v[0]); pk.u[1] = f2bf(v[1]);
                pk.u[2] = f2bf(v[2]); pk.u[3] = f2bf(v[3]);
                *(unsigned long long*)&Asm[r * LDT + c] = pk.q;
            }
        } else {
#pragma unroll
            for (int it = 0; it < 2; ++it) {
                int idx = it * 256 + tid;
                int r = idx >> 2, c = (idx & 3) << 3;
                const unsigned short* g =
                    (const unsigned short*)Ap + (size_t)(bm + r) * K + kt + c;
                *(bf16x8*)&Asm[r * LDT + c] = *(const bf16x8*)g;
            }
        }
#pragma unroll
        for (int it = 0; it < 4; ++it) {
            int idx = it * 256 + tid;
            int r = idx >> 3, c = (idx & 7) << 2;
            const float* g = Bp + (size_t)(bn + r) * K + kt + c;
            f32x4 v = *(const f32x4*)g;
            union { unsigned long long q; unsigned short u[4]; } pk;
            pk.u[0] = f2bf(v[0]); pk.u[1] = f2bf(v[1]);
            pk.u[2] = f2bf(v[2]); pk.u[3] = f2bf(v[3]);
            *(unsigned long long*)&Bsm[r * LDT + c] = pk.q;
        }
        __syncthreads();
        bf16x8 af0 = *(bf16x8*)&Asm[(w * 32 + la) * LDT + lb * 8];
        bf16x8 af1 = *(bf16x8*)&Asm[(w * 32 + 16 + la) * LDT + lb * 8];
#pragma unroll
        for (int nb = 0; nb < 8; ++nb) {
            bf16x8 bfr = *(bf16x8*)&Bsm[(nb * 16 + la) * LDT + lb * 8];
            acc[0][nb] = mfma16(af0, bfr, acc[0][nb]);
            acc[1][nb] = mfma16(af1, bfr, acc[1][nb]);
        }
        __syncthreads();
    }

    const int rbase = bm + w * 32;
    if constexpr (EPI == 0) {
        float* C = (float*)Cp;
#pragma unroll
        for (int mf = 0; mf < 2; ++mf)
#pragma unroll
            for (int nb = 0; nb < 8; ++nb)
#pragma unroll
                for (int r = 0; r < 4; ++r)
                    C[(size_t)(rbase + mf * 16 + lb * 4 + r) * N + bn + nb * 16 + la] =
                        acc[mf][nb][r];
    } else if constexpr (EPI == 1) {
        unsigned short* C = (unsigned short*)Cp;
#pragma unroll
        for (int mf = 0; mf < 2; ++mf) {
#pragma unroll
            for (int r = 0; r < 4; ++r) {
                int m = rbase + mf * 16 + lb * 4 + r;
                const float* cb = cosT + (size_t)m * D_;
                const float* sb = sinT + (size_t)m * D_;
#pragma unroll
                for (int nb = 0; nb < 4; ++nb) {
                    int d = nb * 16 + la;
                    float c = cb[d], s = sb[d];
                    float x1 = acc[mf][nb][r], x2 = acc[mf][nb + 4][r];
                    C[(size_t)m * N + bn + d]      = f2bf((x1 * c - x2 * s) * scale);
                    C[(size_t)m * N + bn + d + 64] = f2bf((x2 * c + x1 * s) * scale);
                }
            }
        }
    } else {
        unsigned short* C = (unsigned short*)Cp;
#pragma unroll
        for (int mf = 0; mf < 2; ++mf)
#pragma unroll
            for (int nb = 0; nb < 8; ++nb)
#pragma unroll
                for (int r = 0; r < 4; ++r) {
                    int m = rbase + mf * 16 + lb * 4 + r;
                    int b = m >> 11, s = m & (S_ - 1);
                    int n = bn + nb * 16 + la;
                    int kv = n >> 7, d = n & 127;
                    C[(((size_t)b * NKV_ + kv) * D_ + d) * S_ + s] =
                        f2bf(acc[mf][nb][r]);
                }
    }
}

// ---------------- flash attention: 4 waves x 32 q-rows, KVBLK=64 --------------
// Q pre-scaled by QSCALE_ (log2 domain). Swapped QK^T (mfma(K,Q)) and swapped
// PV (mfma(V^T,P)) keep softmax stats lane-local: q = la, k = lb*4+r.
__global__ __launch_bounds__(256, 2) void attn2_k(
    const unsigned short* __restrict__ Qw,  // (B,S,NH,D) bf16 * QSCALE
    const unsigned short* __restrict__ Kw,  // (B,S,NKV,D) bf16
    const unsigned short* __restrict__ Vt,  // (B,NKV,D,S) bf16
    unsigned short* __restrict__ Ow)        // (B,S,NH*D) bf16
{
    constexpr int LDP = 72;
    __shared__ __align__(16) unsigned short Ksm[64 * 128];   // [kv][d] swizzled
    __shared__ __align__(16) unsigned short Vsm[128 * 64];   // [d][kv] swizzled
    __shared__ __align__(16) unsigned short Psm[4][32 * LDP];
    const int tid = threadIdx.x, lane = tid & 63, w = tid >> 6;
    const int la = lane & 15, lb = lane >> 4;
    const int blk = blockIdx.x;
    const int qbi = (S_ / 128 - 1) - (blk >> 6);  // heavy blocks first
    const int bh = blk & 63;
    const int b = bh >> 5, h = bh & 31;
    const int kvh = h >> 2;
    const int qb = qbi * 128;
    const int qw0 = qb + w * 32;

    // Q fragments (B-operand layout): fq[mq][kc] = Q[qw0+mq*16+la][kc*32+lb*8..]
    bf16x8 fq[2][4];
    const unsigned short* qp =
        Qw + ((size_t)(b * S_ + qw0 + la) * NH_ + h) * D_ + lb * 8;
#pragma unroll
    for (int mq = 0; mq < 2; ++mq)
#pragma unroll
        for (int kc = 0; kc < 4; ++kc)
            fq[mq][kc] = *(const bf16x8*)(qp + (size_t)mq * 16 * NH_ * D_ + kc * 32);

    float m_[2], l_[2];
    f32x4 oacc[8][2];
    m_[0] = m_[1] = -__builtin_inff();
    l_[0] = l_[1] = 0.f;
#pragma unroll
    for (int db = 0; db < 8; ++db)
#pragma unroll
        for (int mq = 0; mq < 2; ++mq) oacc[db][mq] = f32x4{0.f, 0.f, 0.f, 0.f};

    const int ntiles = (qb + 128) >> 6;
    for (int t = 0; t < ntiles; ++t) {
        const int kv0 = t << 6;
        // ---- stage K tile: linear LDS dest, inverse-swizzled global source
        {
            const int rb = tid >> 4, sl = tid & 15;
#pragma unroll
            for (int it = 0; it < 4; ++it) {
                int row = it * 16 + rb;
                int cc = sl ^ (row & 7);
                const unsigned short* g =
                    Kw + ((size_t)(b * S_ + kv0 + row) * NKV_ + kvh) * D_ + cc * 8;
                gll16(g, &Ksm[(it * 256 + tid) * 8]);
            }
        }
        // ---- stage V^T tile
        {
            const int rb = tid >> 3, sl = tid & 7;
#pragma unroll
            for (int it = 0; it < 4; ++it) {
                int row = it * 32 + rb;
                int cc = sl ^ (row & 7);
                const unsigned short* g =
                    Vt + ((size_t)(b * NKV_ + kvh) * D_ + row) * S_ + kv0 + cc * 8;
                gll16(g, &Vsm[(it * 256 + tid) * 8]);
            }
        }
        __syncthreads();

        if (kv0 < qw0 + 32) {  // wave-uniform causal skip
            // ---- QK^T swapped: sacc[nk][mq], D rows = k, cols = q
            f32x4 sacc[4][2];
#pragma unroll
            for (int nk = 0; nk < 4; ++nk)
#pragma unroll
                for (int mq = 0; mq < 2; ++mq) sacc[nk][mq] = f32x4{0.f, 0.f, 0.f, 0.f};
#pragma unroll
            for (int kc = 0; kc < 4; ++kc) {
#pragma unroll
                for (int nk = 0; nk < 4; ++nk) {
                    int row = nk * 16 + la;
                    int slot = (kc * 4 + lb) ^ (la & 7);
                    bf16x8 fk = *(const bf16x8*)&Ksm[row * 128 + slot * 8];
#pragma unroll
                    for (int mq = 0; mq < 2; ++mq)
                        sacc[nk][mq] = mfma16(fk, fq[mq][kc], sacc[nk][mq]);
                }
            }
            // ---- mask + row max (k = kv0+nk*16+lb*4+r, q = qw0+mq*16+la)
            float pv[4][2][4];
            float pm[2];
#pragma unroll
            for (int mq = 0; mq < 2; ++mq) {
                int q = qw0 + mq * 16 + la;
                float mx = -__builtin_inff();
#pragma unroll
                for (int nk = 0; nk < 4; ++nk)
#pragma unroll
                    for (int r = 0; r < 4; ++r) {
                        int k = kv0 + nk * 16 + lb * 4 + r;
                        float s = (k <= q) ? sacc[nk][mq][r] : -__builtin_inff();
                        pv[nk][mq][r] = s;
                        mx = fmaxf(mx, s);
                    }
                mx = fmaxf(mx, __shfl_xor(mx, 16));
                mx = fmaxf(mx, __shfl_xor(mx, 32));
                pm[mq] = mx;
            }
            float fac[2], tsum[2];
#pragma unroll
            for (int mq = 0; mq < 2; ++mq) {
                float mn = fmaxf(m_[mq], pm[mq]);
                fac[mq] = exp2f(m_[mq] - mn);
                m_[mq] = mn;
                tsum[mq] = 0.f;
            }
#pragma unroll
            for (int nk = 0; nk < 4; ++nk)
#pragma unroll
                for (int mq = 0; mq < 2; ++mq)
#pragma unroll
                    for (int r = 0; r < 4; ++r) {
                        float p = exp2f(pv[nk][mq][r] - m_[mq]);
                        pv[nk][mq][r] = p;
                        tsum[mq] += p;
                    }
#pragma unroll
            for (int mq = 0; mq < 2; ++mq) {
                float s = tsum[mq];
                s += __shfl_xor(s, 16);
                s += __shfl_xor(s, 32);
                l_[mq] = l_[mq] * fac[mq] + s;
            }
#pragma unroll
            for (int db = 0; db < 8; ++db)
#pragma unroll
                for (int mq = 0; mq < 2; ++mq) oacc[db][mq] *= fac[mq];

            // ---- P -> LDS, packed b64 (row q = mq*16+la, cols k consecutive)
            unsigned short* pp = &Psm[w][0];
#pragma unroll
            for (int nk = 0; nk < 4; ++nk)
#pragma unroll
                for (int mq = 0; mq < 2; ++mq) {
                    s16x4 pk;
#pragma unroll
                    for (int r = 0; r < 4; ++r) pk[r] = (short)f2bf(pv[nk][mq][r]);
                    *(s16x4*)&pp[(mq * 16 + la) * LDP + nk * 16 + lb * 4] = pk;
                }
            bf16x8 fp[2][2];
#pragma unroll
            for (int mq = 0; mq < 2; ++mq)
#pragma unroll
                for (int ks = 0; ks < 2; ++ks)
                    fp[mq][ks] =
                        *(const bf16x8*)&pp[(mq * 16 + la) * LDP + ks * 32 + lb * 8];
            // ---- PV swapped: O^T[d][q] += V^T-frag * P-frag
#pragma unroll
            for (int ks = 0; ks < 2; ++ks)
#pragma unroll
                for (int db = 0; db < 8; ++db) {
                    int row = db * 16 + la;
                    int slot = (ks * 4 + lb) ^ (la & 7);
                    bf16x8 fv = *(const bf16x8*)&Vsm[row * 64 + slot * 8];
#pragma unroll
                    for (int mq = 0; mq < 2; ++mq)
                        oacc[db][mq] = mfma16(fv, fp[mq][ks], oacc[db][mq]);
                }
        }
        __syncthreads();
    }

    // ---- normalize + store: O^T frag (db,mq): d = db*16+lb*4+r, q = mq*16+la
#pragma unroll
    for (int mq = 0; mq < 2; ++mq) {
        float rl = 1.f / l_[mq];
        int q = qw0 + mq * 16 + la;
#pragma unroll
        for (int db = 0; db < 8; ++db) {
            f32x4 o = oacc[db][mq];
            s16x4 pk;
#pragma unroll
            for (int r = 0; r < 4; ++r) pk[r] = (short)f2bf(o[r] * rl);
            int d = db * 16 + lb * 4;
            *(s16x4*)(Ow + (size_t)(b * S_ + q) * (NH_ * D_) + h * D_ + d) = pk;
        }
    }
}

extern "C" void kernel_launch(void* const* d_in, const int* in_sizes, int n_in,
                              void* d_out, int out_size, void* d_ws, size_t ws_size,
                              hipStream_t stream) {
    const float* hs   = (const float*)d_in[0];
    const float* cosT = (const float*)d_in[1];
    const float* sinT = (const float*)d_in[2];
    const float* Wq   = (const float*)d_in[3];
    const float* Wk   = (const float*)d_in[4];
    const float* Wv   = (const float*)d_in[5];
    const float* Wo   = (const float*)d_in[6];

    constexpr size_t Qn  = (size_t)B_ * S_ * NH_ * D_;    // 16.77M
    constexpr size_t Kn  = (size_t)B_ * S_ * NKV_ * D_;   // 4.19M
    constexpr size_t Hn  = (size_t)B_ * S_ * HID_;        // 16.77M
    constexpr size_t Wqn = (size_t)NH_ * D_ * HID_;       // 16.77M
    constexpr size_t Wkn = (size_t)NKV_ * D_ * HID_;      // 4.19M

    unsigned short* Qws  = (unsigned short*)d_ws;
    unsigned short* Kws  = Qws + Qn;
    unsigned short* Vtws = Kws + Kn;
    unsigned short* AOws = Vtws + Kn;
    unsigned short* hsb  = AOws + Qn;
    unsigned short* Wqb  = hsb + Hn;
    unsigned short* Wkb  = Wqb + Wqn;
    unsigned short* Wvb  = Wkb + Wkn;
    unsigned short* Wob  = Wvb + Wkn;
    constexpr size_t need = (Qn + 2 * Kn + Qn + Hn + Wqn + 2 * Wkn + Wqn) * 2;

    const int M = B_ * S_;
    dim3 blk(256);

    if (ws_size >= need) {
        // fast path: pre-cast everything to bf16, m97-structure GEMMs
        cast_bf16_k<<<dim3((int)(Hn / 8 / 256)), blk, 0, stream>>>(hs, hsb, (int)(Hn / 8));
        cast_bf16_k<<<dim3((int)(Wqn / 8 / 256)), blk, 0, stream>>>(Wq, Wqb, (int)(Wqn / 8));
        cast_bf16_k<<<dim3((int)(Wkn / 8 / 256)), blk, 0, stream>>>(Wk, Wkb, (int)(Wkn / 8));
        cast_bf16_k<<<dim3((int)(Wkn / 8 / 256)), blk, 0, stream>>>(Wv, Wvb, (int)(Wkn / 8));
        cast_bf16_k<<<dim3((int)(Wqn / 8 / 256)), blk, 0, stream>>>(Wo, Wob, (int)(Wqn / 8));

        gemm_bf16_k<1, 1><<<dim3((M / 128) * (HID_ / 128)), blk, 0, stream>>>(
            hsb, Wqb, Qws, cosT, sinT, M, NH_ * D_, HID_, QSCALE_);
        gemm_bf16_k<1, 1><<<dim3((M / 128) * (NKV_ * D_ / 128)), blk, 0, stream>>>(
            hsb, Wkb, Kws, cosT, sinT, M, NKV_ * D_, HID_, 1.0f);
        gemm_bf16_k<3, 1><<<dim3((M / 128) * (NKV_ * D_ / 128)), blk, 0, stream>>>(
            hsb, Wvb, Vtws, nullptr, nullptr, M, NKV_ * D_, HID_, 0.f);
        attn2_k<<<dim3(B_ * NH_ * (S_ / 128)), blk, 0, stream>>>(Qws, Kws, Vtws, AOws);
        gemm_bf16_k<0, 0><<<dim3((M / 128) * (HID_ / 128)), blk, 0, stream>>>(
            AOws, Wob, (float*)d_out, nullptr, nullptr, M, HID_, NH_ * D_, 0.f);
    } else {
        // fallback: round-1 fp32-staging GEMMs + new attention
        gemm_legacy_k<1, false><<<dim3((M / 128) * (NH_ * D_ / 128)), blk, 0, stream>>>(
            hs, Wq, Qws, cosT, sinT, M, NH_ * D_, HID_, QSCALE_);
        gemm_legacy_k<1, false><<<dim3((M / 128) * (NKV_ * D_ / 128)), blk, 0, stream>>>(
            hs, Wk, Kws, cosT, sinT, M, NKV_ * D_, HID_, 1.0f);
        gemm_legacy_k<3, false><<<dim3((M / 128) * (NKV_ * D_ / 128)), blk, 0, stream>>>(
            hs, Wv, Vtws, nullptr, nullptr, M, NKV_ * D_, HID_, 0.f);
        attn2_k<<<dim3(B_ * NH_ * (S_ / 128)), blk, 0, stream>>>(Qws, Kws, Vtws, AOws);
        gemm_legacy_k<0, true><<<dim3((M / 128) * (HID_ / 128)), blk, 0, stream>>>(
            AOws, Wo, (float*)d_out, nullptr, nullptr, M, HID_, NH_ * D_, 0.f);
    }
}

// Round 3
// 511.629 us; speedup vs baseline: 3.8753x; 1.5295x over previous
//
#include <hip/hip_runtime.h>
#include <hip/hip_bf16.h>

#define DEV __device__ __forceinline__

typedef __attribute__((ext_vector_type(8))) short bf16x8;
typedef __attribute__((ext_vector_type(4))) short s16x4;
typedef __attribute__((ext_vector_type(4))) float f32x4;

constexpr int B_ = 2, S_ = 2048, HID_ = 4096, NH_ = 32, NKV_ = 8, D_ = 128;
constexpr int GROUPS_ = NH_ / NKV_;
// fold 1/sqrt(D) and log2(e) into Q so attention uses exp2 directly
constexpr float QSCALE_ = 0.08838834764831845f * 1.4426950408889634f;

DEV unsigned short f2bf(float x) {
    union { float f; unsigned int u; } v; v.f = x;
    unsigned int r = v.u + 0x7fffu + ((v.u >> 16) & 1u);
    return (unsigned short)(r >> 16);
}

DEV f32x4 mfma16(bf16x8 a, bf16x8 b, f32x4 c) {
    return __builtin_amdgcn_mfma_f32_16x16x32_bf16(a, b, c, 0, 0, 0);
}

DEV void gll16(const void* g, void* l) {
    __builtin_amdgcn_global_load_lds(
        (const __attribute__((address_space(1))) unsigned int*)g,
        (__attribute__((address_space(3))) unsigned int*)l, 16, 0, 0);
}

// ---------------- fp32 -> bf16 cast (vectorized, memory-bound) ----------------
__global__ __launch_bounds__(256) void cast_bf16_k(
    const float* __restrict__ src, unsigned short* __restrict__ dst, int n8)
{
    int i = blockIdx.x * 256 + threadIdx.x;
    if (i >= n8) return;
    const f32x4* s = (const f32x4*)(src + (size_t)i * 8);
    f32x4 a = s[0], b = s[1];
    bf16x8 o;
    o[0] = (short)f2bf(a[0]); o[1] = (short)f2bf(a[1]);
    o[2] = (short)f2bf(a[2]); o[3] = (short)f2bf(a[3]);
    o[4] = (short)f2bf(b[0]); o[5] = (short)f2bf(b[1]);
    o[6] = (short)f2bf(b[2]); o[7] = (short)f2bf(b[3]);
    *(bf16x8*)(dst + (size_t)i * 8) = o;
}

// =============== 256x256 8-phase bf16 GEMM (T2+T3+T4+T5), C = A @ B^T ========
// A: MxK bf16 row-major, B: NxK bf16 row-major. 512 threads = 8 waves (2M x 4N).
// Per-wave 128x64 output via interleaved n-frags: wave wn owns n-frags
// {wn, wn+4, wn+8, wn+12} -> cols (wn+4j)*16+la, so RoPE pair (d,d+64) is
// thread-local (j0/j1 = head A, j2/j3 = head B).
// LDS: 2 x 32KB A-buf + 2 x 32KB B-buf = 128 KiB, XOR-swizzled 16B slots
// (slot ^= row&7), staged linearly with inverse-swizzled global source.
// Half-tiles (consumption order): c0=A.h0(rows 0-63,128-191), c1=B.h0(0-127),
// c2=B.h1(128-255), c3=A.h1(64-127,192-255). Issue c_i for tile t+1 in phase i
// of tile t. Waits: P0 vmcnt(2) confirms c0,c1,c2; P2 vmcnt(4) confirms c3
// (vmcnt(0) on last tile). Never drains mid-loop.
// EPI 0: f32 row-major store. EPI 1: fused QKV epilogue (RoPE Q/K, V^T).
template<int EPI>
__global__ __launch_bounds__(512, 2) void gemm256_k(
    const unsigned short* __restrict__ A, const unsigned short* __restrict__ Bw,
    float* __restrict__ Cf,
    unsigned short* __restrict__ Qo, unsigned short* __restrict__ Ko,
    unsigned short* __restrict__ Vo,
    const float* __restrict__ cosT, const float* __restrict__ sinT,
    int M, int N, int K)
{
    __shared__ __align__(16) unsigned short lds[65536];  // 128 KiB
    const int tid = threadIdx.x, lane = tid & 63;
    const int w = tid >> 6, wm = w >> 2, wn = w & 3;
    const int la = lane & 15, lb = lane >> 4;

    // bijective XCD swizzle (grid % 8 == 0 for all our launches)
    const int nwg = (int)gridDim.x;
    const int cpx = nwg >> 3;
    const int bid = (int)blockIdx.x;
    const int sw = (bid & 7) * cpx + (bid >> 3);
    const int ntn = N >> 8;
    const int bm = (sw / ntn) << 8, bn = (sw % ntn) << 8;

    // staging: thread t covers row (srow + half-offset), 16B col-slot scol8,
    // with inverse swizzle on the global column so swizzled reads see linear data
    const int srow = tid >> 3;                       // 0..63
    const int scol8 = (tid & 7) ^ (srow & 7);        // involution
    const size_t rK = (size_t)K;
    const unsigned short* gA = A + (size_t)(bm + srow) * rK + scol8 * 8;
    const unsigned short* gB = Bw + (size_t)(bn + srow) * rK + scol8 * 8;

#define STAGE_A_H0(buf, kt) { gll16(gA + (size_t)(kt),            &lds[(buf)*16384 + tid*8]); \
                              gll16(gA + (size_t)(kt) + 128*rK,   &lds[(buf)*16384 + 8192 + tid*8]); }
#define STAGE_A_H1(buf, kt) { gll16(gA + (size_t)(kt) + 64*rK,    &lds[(buf)*16384 + 4096 + tid*8]); \
                              gll16(gA + (size_t)(kt) + 192*rK,   &lds[(buf)*16384 + 12288 + tid*8]); }
#define STAGE_B_H0(buf, kt) { gll16(gB + (size_t)(kt),            &lds[32768 + (buf)*16384 + tid*8]); \
                              gll16(gB + (size_t)(kt) + 64*rK,    &lds[32768 + (buf)*16384 + 4096 + tid*8]); }
#define STAGE_B_H1(buf, kt) { gll16(gB + (size_t)(kt) + 128*rK,   &lds[32768 + (buf)*16384 + 8192 + tid*8]); \
                              gll16(gB + (size_t)(kt) + 192*rK,   &lds[32768 + (buf)*16384 + 12288 + tid*8]); }
#define SB0() __builtin_amdgcn_sched_barrier(0)

    f32x4 acc[8][4];
#pragma unroll
    for (int m = 0; m < 8; ++m)
#pragma unroll
        for (int j = 0; j < 4; ++j) acc[m][j] = f32x4{0.f, 0.f, 0.f, 0.f};

    auto rdA = [&](int buf, int m, int kk) -> bf16x8 {
        int r = wm * 128 + m * 16 + la;
        int slot = (kk * 4 + lb) ^ (la & 7);
        return *(const bf16x8*)&lds[buf * 16384 + r * 64 + slot * 8];
    };
    auto rdB = [&](int buf, int j, int kk) -> bf16x8 {
        int r = (wn + 4 * j) * 16 + la;
        int slot = (kk * 4 + lb) ^ (la & 7);
        return *(const bf16x8*)&lds[32768 + buf * 16384 + r * 64 + slot * 8];
    };

    // prologue: tile 0, issue in consumption order c0,c1,c2,c3
    STAGE_A_H0(0, 0); STAGE_B_H0(0, 0); STAGE_B_H1(0, 0); STAGE_A_H1(0, 0);

    bf16x8 af[4][2], b01[2][2], b23[2][2];
    int cur = 0;
    const int nt = K >> 6;
    for (int t = 0; t < nt; ++t) {
        const bool pre = (t + 1 < nt);
        const int kn = (t + 1) << 6;
        const int nb = cur ^ 1;
        // ---------------- P0: frags A(m0-3)+B(j0-1); stage c0; MFMA q(0,0) ----
        asm volatile("s_waitcnt vmcnt(2)" ::: "memory");
        SB0(); __builtin_amdgcn_s_barrier(); SB0();
#pragma unroll
        for (int m = 0; m < 4; ++m)
#pragma unroll
            for (int kk = 0; kk < 2; ++kk) af[m][kk] = rdA(cur, m, kk);
#pragma unroll
        for (int j = 0; j < 2; ++j)
#pragma unroll
            for (int kk = 0; kk < 2; ++kk) b01[j][kk] = rdB(cur, j, kk);
        if (pre) STAGE_A_H0(nb, kn);
        __builtin_amdgcn_s_setprio(1);
#pragma unroll
        for (int kk = 0; kk < 2; ++kk)
#pragma unroll
            for (int m = 0; m < 4; ++m)
#pragma unroll
                for (int j = 0; j < 2; ++j)
                    acc[m][j] = mfma16(af[m][kk], b01[j][kk], acc[m][j]);
        __builtin_amdgcn_s_setprio(0);
        // ---------------- P1: frags B(j2-3); stage c1; MFMA q(0,1) ----------
        SB0(); __builtin_amdgcn_s_barrier(); SB0();
#pragma unroll
        for (int j = 0; j < 2; ++j)
#pragma unroll
            for (int kk = 0; kk < 2; ++kk) b23[j][kk] = rdB(cur, j + 2, kk);
        if (pre) STAGE_B_H0(nb, kn);
        __builtin_amdgcn_s_setprio(1);
#pragma unroll
        for (int kk = 0; kk < 2; ++kk)
#pragma unroll
            for (int m = 0; m < 4; ++m)
#pragma unroll
                for (int j = 0; j < 2; ++j)
                    acc[m][j + 2] = mfma16(af[m][kk], b23[j][kk], acc[m][j + 2]);
        __builtin_amdgcn_s_setprio(0);
        // ---------------- P2: frags A(m4-7); stage c2; MFMA q(1,1) ----------
        if (pre) { asm volatile("s_waitcnt vmcnt(4)" ::: "memory"); }
        else     { asm volatile("s_waitcnt vmcnt(0)" ::: "memory"); }
        SB0(); __builtin_amdgcn_s_barrier(); SB0();
#pragma unroll
        for (int m = 0; m < 4; ++m)
#pragma unroll
            for (int kk = 0; kk < 2; ++kk) af[m][kk] = rdA(cur, m + 4, kk);
        if (pre) STAGE_B_H1(nb, kn);
        __builtin_amdgcn_s_setprio(1);
#pragma unroll
        for (int kk = 0; kk < 2; ++kk)
#pragma unroll
            for (int m = 0; m < 4; ++m)
#pragma unroll
                for (int j = 0; j < 2; ++j)
                    acc[m + 4][j + 2] = mfma16(af[m][kk], b23[j][kk], acc[m + 4][j + 2]);
        __builtin_amdgcn_s_setprio(0);
        // ---------------- P3: no frags; stage c3; MFMA q(1,0) ---------------
        SB0(); __builtin_amdgcn_s_barrier(); SB0();
        if (pre) STAGE_A_H1(nb, kn);
        __builtin_amdgcn_s_setprio(1);
#pragma unroll
        for (int kk = 0; kk < 2; ++kk)
#pragma unroll
            for (int m = 0; m < 4; ++m)
#pragma unroll
                for (int j = 0; j < 2; ++j)
                    acc[m + 4][j] = mfma16(af[m][kk], b01[j][kk], acc[m + 4][j]);
        __builtin_amdgcn_s_setprio(0);
        cur ^= 1;
    }
#undef STAGE_A_H0
#undef STAGE_A_H1
#undef STAGE_B_H0
#undef STAGE_B_H1
#undef SB0

    // ---------------- epilogue ----------------
    const int srow0 = bm + wm * 128;
    if constexpr (EPI == 0) {
#pragma unroll
        for (int m = 0; m < 8; ++m)
#pragma unroll
            for (int j = 0; j < 4; ++j) {
                int col = bn + (wn + 4 * j) * 16 + la;
#pragma unroll
                for (int r = 0; r < 4; ++r)
                    Cf[(size_t)(srow0 + m * 16 + lb * 4 + r) * N + col] = acc[m][j][r];
            }
    } else {
        if (bn < 5120) {
            // Q (bn<4096) or K: RoPE epilogue. j0/j1 = head hbase, j2/j3 = hbase+1
            unsigned short* dst; int ld, hbase; float scale;
            if (bn < 4096) { dst = Qo; ld = NH_ * D_; hbase = bn >> 7; scale = QSCALE_; }
            else           { dst = Ko; ld = NKV_ * D_; hbase = (bn - 4096) >> 7; scale = 1.f; }
            const int d = wn * 16 + la;  // < 64; cos[d]==cos[d+64]
#pragma unroll
            for (int m = 0; m < 8; ++m) {
#pragma unroll
                for (int r = 0; r < 4; ++r) {
                    int row = srow0 + m * 16 + lb * 4 + r;  // = b*S + s
                    float cv = cosT[(size_t)row * D_ + d];
                    float sv = sinT[(size_t)row * D_ + d];
#pragma unroll
                    for (int p = 0; p < 2; ++p) {
                        float x1 = acc[m][p * 2 + 0][r], x2 = acc[m][p * 2 + 1][r];
                        unsigned short* o = dst + (size_t)row * ld + (hbase + p) * D_ + d;
                        o[0]  = f2bf((x1 * cv - x2 * sv) * scale);
                        o[64] = f2bf((x2 * cv + x1 * sv) * scale);
                    }
                }
            }
        } else {
            // V: transposed store (B, NKV, D, S)
            const int col0 = bn - 5120;
#pragma unroll
            for (int m = 0; m < 8; ++m) {
                int row = srow0 + m * 16 + lb * 4;
                int b = row >> 11, s = row & (S_ - 1);
#pragma unroll
                for (int j = 0; j < 4; ++j) {
                    int c = col0 + (wn + 4 * j) * 16 + la;
                    int kv = c >> 7, d = c & 127;
                    s16x4 pk;
#pragma unroll
                    for (int r = 0; r < 4; ++r) pk[r] = (short)f2bf(acc[m][j][r]);
                    *(s16x4*)&Vo[((size_t)(b * NKV_ + kv) * D_ + d) * S_ + s] = pk;
                }
            }
        }
    }
}

// ---------------- legacy fp32-input GEMM (round-1 structure, ws fallback) -----
template<int EPI, bool ABF16>
__global__ __launch_bounds__(256) void gemm_legacy_k(
    const void* __restrict__ Ap, const float* __restrict__ Bp,
    void* __restrict__ Cp, const float* __restrict__ cosT,
    const float* __restrict__ sinT, int M, int N, int K, float scale)
{
    constexpr int LDT = 40;
    __shared__ __align__(16) unsigned short Asm[128 * LDT];
    __shared__ __align__(16) unsigned short Bsm[128 * LDT];
    const int tid = threadIdx.x;
    const int lane = tid & 63;
    const int w = tid >> 6;
    const int la = lane & 15, lb = lane >> 4;
    const int ntn = N >> 7;
    const int bm = (int)(blockIdx.x / ntn) << 7;
    const int bn = (int)(blockIdx.x % ntn) << 7;

    f32x4 acc[2][8];
#pragma unroll
    for (int i = 0; i < 2; ++i)
#pragma unroll
        for (int j = 0; j < 8; ++j) acc[i][j] = f32x4{0.f, 0.f, 0.f, 0.f};

    for (int kt = 0; kt < K; kt += 32) {
        if constexpr (!ABF16) {
#pragma unroll
            for (int it = 0; it < 4; ++it) {
                int idx = it * 256 + tid;
                int r = idx >> 3, c = (idx & 7) << 2;
                const float* g = (const float*)Ap + (size_t)(bm + r) * K + kt + c;
                f32x4 v = *(const f32x4*)g;
                union { unsigned long long q; unsigned short u[4]; } pk;
                pk.u[0] = f2bf(v[0]); pk.u[1] = f2bf(v[1]);
                pk.u[2] = f2bf(v[2]); pk.u[3] = f2bf(v[3]);
                *(unsigned long long*)&Asm[r * LDT + c] = pk.q;
            }
        } else {
#pragma unroll
            for (int it = 0; it < 2; ++it) {
                int idx = it * 256 + tid;
                int r = idx >> 2, c = (idx & 3) << 3;
                const unsigned short* g =
                    (const unsigned short*)Ap + (size_t)(bm + r) * K + kt + c;
                *(bf16x8*)&Asm[r * LDT + c] = *(const bf16x8*)g;
            }
        }
#pragma unroll
        for (int it = 0; it < 4; ++it) {
            int idx = it * 256 + tid;
            int r = idx >> 3, c = (idx & 7) << 2;
            const float* g = Bp + (size_t)(bn + r) * K + kt + c;
            f32x4 v = *(const f32x4*)g;
            union { unsigned long long q; unsigned short u[4]; } pk;
            pk.u[0] = f2bf(v[0]); pk.u[1] = f2bf(v[1]);
            pk.u[2] = f2bf(v[2]); pk.u[3] = f2bf(v[3]);
            *(unsigned long long*)&Bsm[r * LDT + c] = pk.q;
        }
        __syncthreads();
        bf16x8 af0 = *(bf16x8*)&Asm[(w * 32 + la) * LDT + lb * 8];
        bf16x8 af1 = *(bf16x8*)&Asm[(w * 32 + 16 + la) * LDT + lb * 8];
#pragma unroll
        for (int nb = 0; nb < 8; ++nb) {
            bf16x8 bfr = *(bf16x8*)&Bsm[(nb * 16 + la) * LDT + lb * 8];
            acc[0][nb] = mfma16(af0, bfr, acc[0][nb]);
            acc[1][nb] = mfma16(af1, bfr, acc[1][nb]);
        }
        __syncthreads();
    }

    const int rbase = bm + w * 32;
    if constexpr (EPI == 0) {
        float* C = (float*)Cp;
#pragma unroll
        for (int mf = 0; mf < 2; ++mf)
#pragma unroll
            for (int nb = 0; nb < 8; ++nb)
#pragma unroll
                for (int r = 0; r < 4; ++r)
                    C[(size_t)(rbase + mf * 16 + lb * 4 + r) * N + bn + nb * 16 + la] =
                        acc[mf][nb][r];
    } else if constexpr (EPI == 1) {
        unsigned short* C = (unsigned short*)Cp;
#pragma unroll
        for (int mf = 0; mf < 2; ++mf) {
#pragma unroll
            for (int r = 0; r < 4; ++r) {
                int m = rbase + mf * 16 + lb * 4 + r;
                const float* cb = cosT + (size_t)m * D_;
                const float* sb = sinT + (size_t)m * D_;
#pragma unroll
                for (int nb = 0; nb < 4; ++nb) {
                    int d = nb * 16 + la;
                    float c = cb[d], s = sb[d];
                    float x1 = acc[mf][nb][r], x2 = acc[mf][nb + 4][r];
                    C[(size_t)m * N + bn + d]      = f2bf((x1 * c - x2 * s) * scale);
                    C[(size_t)m * N + bn + d + 64] = f2bf((x2 * c + x1 * s) * scale);
                }
            }
        }
    } else {
        unsigned short* C = (unsigned short*)Cp;
#pragma unroll
        for (int mf = 0; mf < 2; ++mf)
#pragma unroll
            for (int nb = 0; nb < 8; ++nb)
#pragma unroll
                for (int r = 0; r < 4; ++r) {
                    int m = rbase + mf * 16 + lb * 4 + r;
                    int b = m >> 11, s = m & (S_ - 1);
                    int n = bn + nb * 16 + la;
                    int kv = n >> 7, d = n & 127;
                    C[(((size_t)b * NKV_ + kv) * D_ + d) * S_ + s] =
                        f2bf(acc[mf][nb][r]);
                }
    }
}

// ---------------- flash attention: 4 waves x 32 q-rows, KVBLK=64 --------------
__global__ __launch_bounds__(256, 2) void attn2_k(
    const unsigned short* __restrict__ Qw,  // (B,S,NH,D) bf16 * QSCALE
    const unsigned short* __restrict__ Kw,  // (B,S,NKV,D) bf16
    const unsigned short* __restrict__ Vt,  // (B,NKV,D,S) bf16
    unsigned short* __restrict__ Ow)        // (B,S,NH*D) bf16
{
    constexpr int LDP = 72;
    __shared__ __align__(16) unsigned short Ksm[64 * 128];
    __shared__ __align__(16) unsigned short Vsm[128 * 64];
    __shared__ __align__(16) unsigned short Psm[4][32 * LDP];
    const int tid = threadIdx.x, lane = tid & 63, w = tid >> 6;
    const int la = lane & 15, lb = lane >> 4;
    const int blk = blockIdx.x;
    const int qbi = (S_ / 128 - 1) - (blk >> 6);  // heavy blocks first
    const int bh = blk & 63;
    const int b = bh >> 5, h = bh & 31;
    const int kvh = h >> 2;
    const int qb = qbi * 128;
    const int qw0 = qb + w * 32;

    bf16x8 fq[2][4];
    const unsigned short* qp =
        Qw + ((size_t)(b * S_ + qw0 + la) * NH_ + h) * D_ + lb * 8;
#pragma unroll
    for (int mq = 0; mq < 2; ++mq)
#pragma unroll
        for (int kc = 0; kc < 4; ++kc)
            fq[mq][kc] = *(const bf16x8*)(qp + (size_t)mq * 16 * NH_ * D_ + kc * 32);

    float m_[2], l_[2];
    f32x4 oacc[8][2];
    m_[0] = m_[1] = -__builtin_inff();
    l_[0] = l_[1] = 0.f;
#pragma unroll
    for (int db = 0; db < 8; ++db)
#pragma unroll
        for (int mq = 0; mq < 2; ++mq) oacc[db][mq] = f32x4{0.f, 0.f, 0.f, 0.f};

    const int ntiles = (qb + 128) >> 6;
    for (int t = 0; t < ntiles; ++t) {
        const int kv0 = t << 6;
        {
            const int rb = tid >> 4, sl = tid & 15;
#pragma unroll
            for (int it = 0; it < 4; ++it) {
                int row = it * 16 + rb;
                int cc = sl ^ (row & 7);
                const unsigned short* g =
                    Kw + ((size_t)(b * S_ + kv0 + row) * NKV_ + kvh) * D_ + cc * 8;
                gll16(g, &Ksm[(it * 256 + tid) * 8]);
            }
        }
        {
            const int rb = tid >> 3, sl = tid & 7;
#pragma unroll
            for (int it = 0; it < 4; ++it) {
                int row = it * 32 + rb;
                int cc = sl ^ (row & 7);
                const unsigned short* g =
                    Vt + ((size_t)(b * NKV_ + kvh) * D_ + row) * S_ + kv0 + cc * 8;
                gll16(g, &Vsm[(it * 256 + tid) * 8]);
            }
        }
        __syncthreads();

        if (kv0 < qw0 + 32) {
            f32x4 sacc[4][2];
#pragma unroll
            for (int nk = 0; nk < 4; ++nk)
#pragma unroll
                for (int mq = 0; mq < 2; ++mq) sacc[nk][mq] = f32x4{0.f, 0.f, 0.f, 0.f};
#pragma unroll
            for (int kc = 0; kc < 4; ++kc) {
#pragma unroll
                for (int nk = 0; nk < 4; ++nk) {
                    int row = nk * 16 + la;
                    int slot = (kc * 4 + lb) ^ (la & 7);
                    bf16x8 fk = *(const bf16x8*)&Ksm[row * 128 + slot * 8];
#pragma unroll
                    for (int mq = 0; mq < 2; ++mq)
                        sacc[nk][mq] = mfma16(fk, fq[mq][kc], sacc[nk][mq]);
                }
            }
            const int qrow0 = qw0;
            float pv[4][2][4];
            float pm[2];
#pragma unroll
            for (int mq = 0; mq < 2; ++mq) {
                int q = qrow0 + mq * 16 + la;
                float mx = -__builtin_inff();
#pragma unroll
                for (int nk = 0; nk < 4; ++nk)
#pragma unroll
                    for (int r = 0; r < 4; ++r) {
                        int k = kv0 + nk * 16 + lb * 4 + r;
                        float s = (k <= q) ? sacc[nk][mq][r] : -__builtin_inff();
                        pv[nk][mq][r] = s;
                        mx = fmaxf(mx, s);
                    }
                mx = fmaxf(mx, __shfl_xor(mx, 16));
                mx = fmaxf(mx, __shfl_xor(mx, 32));
                pm[mq] = mx;
            }
            float fac[2], tsum[2];
#pragma unroll
            for (int mq = 0; mq < 2; ++mq) {
                float mn = fmaxf(m_[mq], pm[mq]);
                fac[mq] = exp2f(m_[mq] - mn);
                m_[mq] = mn;
                tsum[mq] = 0.f;
            }
#pragma unroll
            for (int nk = 0; nk < 4; ++nk)
#pragma unroll
                for (int mq = 0; mq < 2; ++mq)
#pragma unroll
                    for (int r = 0; r < 4; ++r) {
                        float p = exp2f(pv[nk][mq][r] - m_[mq]);
                        pv[nk][mq][r] = p;
                        tsum[mq] += p;
                    }
#pragma unroll
            for (int mq = 0; mq < 2; ++mq) {
                float s = tsum[mq];
                s += __shfl_xor(s, 16);
                s += __shfl_xor(s, 32);
                l_[mq] = l_[mq] * fac[mq] + s;
            }
#pragma unroll
            for (int db = 0; db < 8; ++db)
#pragma unroll
                for (int mq = 0; mq < 2; ++mq) oacc[db][mq] *= fac[mq];

            unsigned short* pp = &Psm[w][0];
#pragma unroll
            for (int nk = 0; nk < 4; ++nk)
#pragma unroll
                for (int mq = 0; mq < 2; ++mq) {
                    s16x4 pk;
#pragma unroll
                    for (int r = 0; r < 4; ++r) pk[r] = (short)f2bf(pv[nk][mq][r]);
                    *(s16x4*)&pp[(mq * 16 + la) * LDP + nk * 16 + lb * 4] = pk;
                }
            bf16x8 fp[2][2];
#pragma unroll
            for (int mq = 0; mq < 2; ++mq)
#pragma unroll
                for (int ks = 0; ks < 2; ++ks)
                    fp[mq][ks] =
                        *(const bf16x8*)&pp[(mq * 16 + la) * LDP + ks * 32 + lb * 8];
#pragma unroll
            for (int ks = 0; ks < 2; ++ks)
#pragma unroll
                for (int db = 0; db < 8; ++db) {
                    int row = db * 16 + la;
                    int slot = (ks * 4 + lb) ^ (la & 7);
                    bf16x8 fv = *(const bf16x8*)&Vsm[row * 64 + slot * 8];
#pragma unroll
                    for (int mq = 0; mq < 2; ++mq)
                        oacc[db][mq] = mfma16(fv, fp[mq][ks], oacc[db][mq]);
                }
        }
        __syncthreads();
    }

#pragma unroll
    for (int mq = 0; mq < 2; ++mq) {
        float rl = 1.f / l_[mq];
        int q = qw0 + mq * 16 + la;
#pragma unroll
        for (int db = 0; db < 8; ++db) {
            f32x4 o = oacc[db][mq];
            s16x4 pk;
#pragma unroll
            for (int r = 0; r < 4; ++r) pk[r] = (short)f2bf(o[r] * rl);
            int d = db * 16 + lb * 4;
            *(s16x4*)(Ow + (size_t)(b * S_ + q) * (NH_ * D_) + h * D_ + d) = pk;
        }
    }
}

extern "C" void kernel_launch(void* const* d_in, const int* in_sizes, int n_in,
                              void* d_out, int out_size, void* d_ws, size_t ws_size,
                              hipStream_t stream) {
    const float* hs   = (const float*)d_in[0];
    const float* cosT = (const float*)d_in[1];
    const float* sinT = (const float*)d_in[2];
    const float* Wq   = (const float*)d_in[3];
    const float* Wk   = (const float*)d_in[4];
    const float* Wv   = (const float*)d_in[5];
    const float* Wo   = (const float*)d_in[6];

    constexpr size_t Qn  = (size_t)B_ * S_ * NH_ * D_;    // 16.77M
    constexpr size_t Kn  = (size_t)B_ * S_ * NKV_ * D_;   // 4.19M
    constexpr size_t Hn  = (size_t)B_ * S_ * HID_;        // 16.77M
    constexpr size_t Wqn = (size_t)NH_ * D_ * HID_;       // 16.77M
    constexpr size_t Wkn = (size_t)NKV_ * D_ * HID_;      // 4.19M

    unsigned short* Qws   = (unsigned short*)d_ws;
    unsigned short* Kws   = Qws + Qn;
    unsigned short* Vtws  = Kws + Kn;
    unsigned short* AOws  = Vtws + Kn;
    unsigned short* hsb   = AOws + Qn;
    unsigned short* Wqkvb = hsb + Hn;                  // stacked (6144, 4096)
    unsigned short* Wob   = Wqkvb + Wqn + 2 * Wkn;
    constexpr size_t need = (Qn + 2 * Kn + Qn + Hn + Wqn + 2 * Wkn + Wqn) * 2;

    const int M = B_ * S_;
    dim3 blk(256);

    if (ws_size >= need) {
        // pre-cast everything to bf16 (Wq/Wk/Wv stacked into Wqkvb)
        cast_bf16_k<<<dim3((int)(Hn / 8 / 256)), blk, 0, stream>>>(hs, hsb, (int)(Hn / 8));
        cast_bf16_k<<<dim3((int)(Wqn / 8 / 256)), blk, 0, stream>>>(Wq, Wqkvb, (int)(Wqn / 8));
        cast_bf16_k<<<dim3((int)(Wkn / 8 / 256)), blk, 0, stream>>>(Wk, Wqkvb + Wqn, (int)(Wkn / 8));
        cast_bf16_k<<<dim3((int)(Wkn / 8 / 256)), blk, 0, stream>>>(Wv, Wqkvb + Wqn + Wkn, (int)(Wkn / 8));
        cast_bf16_k<<<dim3((int)(Wqn / 8 / 256)), blk, 0, stream>>>(Wo, Wob, (int)(Wqn / 8));

        // fused QKV: C = hs @ Wqkv^T (M=4096, N=6144), 8-phase 256^2 schedule
        gemm256_k<1><<<dim3((M / 256) * (6144 / 256)), dim3(512), 0, stream>>>(
            hsb, Wqkvb, nullptr, Qws, Kws, Vtws, cosT, sinT, M, 6144, HID_);
        attn2_k<<<dim3(B_ * NH_ * (S_ / 128)), blk, 0, stream>>>(Qws, Kws, Vtws, AOws);
        // out = AO @ Wo^T (f32 epilogue)
        gemm256_k<0><<<dim3((M / 256) * (HID_ / 256)), dim3(512), 0, stream>>>(
            AOws, Wob, (float*)d_out, nullptr, nullptr, nullptr, nullptr, nullptr,
            M, HID_, NH_ * D_);
    } else {
        // fallback: fp32-staging GEMMs + attention
        unsigned short* Qf = (unsigned short*)d_ws;
        unsigned short* Kf = Qf + Qn;
        unsigned short* Vf = Kf + Kn;
        unsigned short* AOf = Vf + Kn;
        gemm_legacy_k<1, false><<<dim3((M / 128) * (NH_ * D_ / 128)), blk, 0, stream>>>(
            hs, Wq, Qf, cosT, sinT, M, NH_ * D_, HID_, QSCALE_);
        gemm_legacy_k<1, false><<<dim3((M / 128) * (NKV_ * D_ / 128)), blk, 0, stream>>>(
            hs, Wk, Kf, cosT, sinT, M, NKV_ * D_, HID_, 1.0f);
        gemm_legacy_k<3, false><<<dim3((M / 128) * (NKV_ * D_ / 128)), blk, 0, stream>>>(
            hs, Wv, Vf, nullptr, nullptr, M, NKV_ * D_, HID_, 0.f);
        attn2_k<<<dim3(B_ * NH_ * (S_ / 128)), blk, 0, stream>>>(Qf, Kf, Vf, AOf);
        gemm_legacy_k<0, true><<<dim3((M / 128) * (HID_ / 128)), blk, 0, stream>>>(
            AOf, Wo, (float*)d_out, nullptr, nullptr, M, HID_, NH_ * D_, 0.f);
    }
}

// Round 4
// 479.478 us; speedup vs baseline: 4.1352x; 1.0671x over previous
//
#include <hip/hip_runtime.h>
#include <hip/hip_bf16.h>

#define DEV __device__ __forceinline__

typedef __attribute__((ext_vector_type(8))) short bf16x8;
typedef __attribute__((ext_vector_type(4))) short s16x4;
typedef __attribute__((ext_vector_type(4))) float f32x4;

constexpr int B_ = 2, S_ = 2048, HID_ = 4096, NH_ = 32, NKV_ = 8, D_ = 128;
constexpr int GROUPS_ = NH_ / NKV_;
// fold 1/sqrt(D) and log2(e) into Q so attention uses exp2 directly
constexpr float QSCALE_ = 0.08838834764831845f * 1.4426950408889634f;

DEV unsigned short f2bf(float x) {
    union { float f; unsigned int u; } v; v.f = x;
    unsigned int r = v.u + 0x7fffu + ((v.u >> 16) & 1u);
    return (unsigned short)(r >> 16);
}

DEV f32x4 mfma16(bf16x8 a, bf16x8 b, f32x4 c) {
    return __builtin_amdgcn_mfma_f32_16x16x32_bf16(a, b, c, 0, 0, 0);
}

DEV void gll16(const void* g, void* l) {
    __builtin_amdgcn_global_load_lds(
        (const __attribute__((address_space(1))) unsigned int*)g,
        (__attribute__((address_space(3))) unsigned int*)l, 16, 0, 0);
}

// ---------------- merged fp32 -> bf16 cast (one launch, 5 segments) ----------
// block ranges: [0,8192) hs, [8192,16384) Wq, [16384,18432) Wk,
// [18432,20480) Wv, [20480,28672) Wo
__global__ __launch_bounds__(256) void cast_all_k(
    const float* __restrict__ s0, const float* __restrict__ s1,
    const float* __restrict__ s2, const float* __restrict__ s3,
    const float* __restrict__ s4,
    unsigned short* __restrict__ d0, unsigned short* __restrict__ d1,
    unsigned short* __restrict__ d2, unsigned short* __restrict__ d3,
    unsigned short* __restrict__ d4)
{
    int bb = blockIdx.x;
    const float* s; unsigned short* d; int off;
    if      (bb < 8192)  { s = s0; d = d0; off = bb; }
    else if (bb < 16384) { s = s1; d = d1; off = bb - 8192; }
    else if (bb < 18432) { s = s2; d = d2; off = bb - 16384; }
    else if (bb < 20480) { s = s3; d = d3; off = bb - 18432; }
    else                 { s = s4; d = d4; off = bb - 20480; }
    size_t i = ((size_t)off * 256 + threadIdx.x) * 8;
    const f32x4* sp = (const f32x4*)(s + i);
    f32x4 a = sp[0], b = sp[1];
    bf16x8 o;
    o[0] = (short)f2bf(a[0]); o[1] = (short)f2bf(a[1]);
    o[2] = (short)f2bf(a[2]); o[3] = (short)f2bf(a[3]);
    o[4] = (short)f2bf(b[0]); o[5] = (short)f2bf(b[1]);
    o[6] = (short)f2bf(b[2]); o[7] = (short)f2bf(b[3]);
    *(bf16x8*)(d + i) = o;
}

// =============== 256x256 8-phase bf16 GEMM (T2+T3+T4+T5), C = A @ B^T ========
// EPI 0: f32 row-major store. EPI 1: Q RoPE epilogue (N=4096 launch).
template<int EPI>
__global__ __launch_bounds__(512, 2) void gemm256_k(
    const unsigned short* __restrict__ A, const unsigned short* __restrict__ Bw,
    float* __restrict__ Cf, unsigned short* __restrict__ Qo,
    const float* __restrict__ cosT, const float* __restrict__ sinT,
    int M, int N, int K)
{
    __shared__ __align__(16) unsigned short lds[65536];  // 128 KiB
    const int tid = threadIdx.x, lane = tid & 63;
    const int w = tid >> 6, wm = w >> 2, wn = w & 3;
    const int la = lane & 15, lb = lane >> 4;

    const int nwg = (int)gridDim.x;
    const int cpx = nwg >> 3;
    const int bid = (int)blockIdx.x;
    const int sw = (bid & 7) * cpx + (bid >> 3);
    const int ntn = N >> 8;
    const int bm = (sw / ntn) << 8, bn = (sw % ntn) << 8;

    const int srow = tid >> 3;                       // 0..63
    const int scol8 = (tid & 7) ^ (srow & 7);        // involution
    const size_t rK = (size_t)K;
    const unsigned short* gA = A + (size_t)(bm + srow) * rK + scol8 * 8;
    const unsigned short* gB = Bw + (size_t)(bn + srow) * rK + scol8 * 8;

#define STAGE_A_H0(buf, kt) { gll16(gA + (size_t)(kt),            &lds[(buf)*16384 + tid*8]); \
                              gll16(gA + (size_t)(kt) + 128*rK,   &lds[(buf)*16384 + 8192 + tid*8]); }
#define STAGE_A_H1(buf, kt) { gll16(gA + (size_t)(kt) + 64*rK,    &lds[(buf)*16384 + 4096 + tid*8]); \
                              gll16(gA + (size_t)(kt) + 192*rK,   &lds[(buf)*16384 + 12288 + tid*8]); }
#define STAGE_B_H0(buf, kt) { gll16(gB + (size_t)(kt),            &lds[32768 + (buf)*16384 + tid*8]); \
                              gll16(gB + (size_t)(kt) + 64*rK,    &lds[32768 + (buf)*16384 + 4096 + tid*8]); }
#define STAGE_B_H1(buf, kt) { gll16(gB + (size_t)(kt) + 128*rK,   &lds[32768 + (buf)*16384 + 8192 + tid*8]); \
                              gll16(gB + (size_t)(kt) + 192*rK,   &lds[32768 + (buf)*16384 + 12288 + tid*8]); }
#define SB0() __builtin_amdgcn_sched_barrier(0)

    f32x4 acc[8][4];
#pragma unroll
    for (int m = 0; m < 8; ++m)
#pragma unroll
        for (int j = 0; j < 4; ++j) acc[m][j] = f32x4{0.f, 0.f, 0.f, 0.f};

    auto rdA = [&](int buf, int m, int kk) -> bf16x8 {
        int r = wm * 128 + m * 16 + la;
        int slot = (kk * 4 + lb) ^ (la & 7);
        return *(const bf16x8*)&lds[buf * 16384 + r * 64 + slot * 8];
    };
    auto rdB = [&](int buf, int j, int kk) -> bf16x8 {
        int r = (wn + 4 * j) * 16 + la;
        int slot = (kk * 4 + lb) ^ (la & 7);
        return *(const bf16x8*)&lds[32768 + buf * 16384 + r * 64 + slot * 8];
    };

    STAGE_A_H0(0, 0); STAGE_B_H0(0, 0); STAGE_B_H1(0, 0); STAGE_A_H1(0, 0);

    bf16x8 af[4][2], b01[2][2], b23[2][2];
    int cur = 0;
    const int nt = K >> 6;
    for (int t = 0; t < nt; ++t) {
        const bool pre = (t + 1 < nt);
        const int kn = (t + 1) << 6;
        const int nb = cur ^ 1;
        // P0
        asm volatile("s_waitcnt vmcnt(2)" ::: "memory");
        SB0(); __builtin_amdgcn_s_barrier(); SB0();
#pragma unroll
        for (int m = 0; m < 4; ++m)
#pragma unroll
            for (int kk = 0; kk < 2; ++kk) af[m][kk] = rdA(cur, m, kk);
#pragma unroll
        for (int j = 0; j < 2; ++j)
#pragma unroll
            for (int kk = 0; kk < 2; ++kk) b01[j][kk] = rdB(cur, j, kk);
        if (pre) STAGE_A_H0(nb, kn);
        __builtin_amdgcn_s_setprio(1);
#pragma unroll
        for (int kk = 0; kk < 2; ++kk)
#pragma unroll
            for (int m = 0; m < 4; ++m)
#pragma unroll
                for (int j = 0; j < 2; ++j)
                    acc[m][j] = mfma16(af[m][kk], b01[j][kk], acc[m][j]);
        __builtin_amdgcn_s_setprio(0);
        // P1
        SB0(); __builtin_amdgcn_s_barrier(); SB0();
#pragma unroll
        for (int j = 0; j < 2; ++j)
#pragma unroll
            for (int kk = 0; kk < 2; ++kk) b23[j][kk] = rdB(cur, j + 2, kk);
        if (pre) STAGE_B_H0(nb, kn);
        __builtin_amdgcn_s_setprio(1);
#pragma unroll
        for (int kk = 0; kk < 2; ++kk)
#pragma unroll
            for (int m = 0; m < 4; ++m)
#pragma unroll
                for (int j = 0; j < 2; ++j)
                    acc[m][j + 2] = mfma16(af[m][kk], b23[j][kk], acc[m][j + 2]);
        __builtin_amdgcn_s_setprio(0);
        // P2
        if (pre) { asm volatile("s_waitcnt vmcnt(4)" ::: "memory"); }
        else     { asm volatile("s_waitcnt vmcnt(0)" ::: "memory"); }
        SB0(); __builtin_amdgcn_s_barrier(); SB0();
#pragma unroll
        for (int m = 0; m < 4; ++m)
#pragma unroll
            for (int kk = 0; kk < 2; ++kk) af[m][kk] = rdA(cur, m + 4, kk);
        if (pre) STAGE_B_H1(nb, kn);
        __builtin_amdgcn_s_setprio(1);
#pragma unroll
        for (int kk = 0; kk < 2; ++kk)
#pragma unroll
            for (int m = 0; m < 4; ++m)
#pragma unroll
                for (int j = 0; j < 2; ++j)
                    acc[m + 4][j + 2] = mfma16(af[m][kk], b23[j][kk], acc[m + 4][j + 2]);
        __builtin_amdgcn_s_setprio(0);
        // P3
        SB0(); __builtin_amdgcn_s_barrier(); SB0();
        if (pre) STAGE_A_H1(nb, kn);
        __builtin_amdgcn_s_setprio(1);
#pragma unroll
        for (int kk = 0; kk < 2; ++kk)
#pragma unroll
            for (int m = 0; m < 4; ++m)
#pragma unroll
                for (int j = 0; j < 2; ++j)
                    acc[m + 4][j] = mfma16(af[m][kk], b01[j][kk], acc[m + 4][j]);
        __builtin_amdgcn_s_setprio(0);
        cur ^= 1;
    }
#undef STAGE_A_H0
#undef STAGE_A_H1
#undef STAGE_B_H0
#undef STAGE_B_H1

    const int srow0 = bm + wm * 128;
    if constexpr (EPI == 0) {
#pragma unroll
        for (int m = 0; m < 8; ++m)
#pragma unroll
            for (int j = 0; j < 4; ++j) {
                int col = bn + (wn + 4 * j) * 16 + la;
#pragma unroll
                for (int r = 0; r < 4; ++r)
                    Cf[(size_t)(srow0 + m * 16 + lb * 4 + r) * N + col] = acc[m][j][r];
            }
    } else {
        // Q RoPE: j0/j1 = head hbase, j2/j3 = head hbase+1
        const int hbase = bn >> 7;
        const int d = wn * 16 + la;  // < 64; cos[d]==cos[d+64]
#pragma unroll
        for (int m = 0; m < 8; ++m) {
#pragma unroll
            for (int r = 0; r < 4; ++r) {
                int row = srow0 + m * 16 + lb * 4 + r;  // = b*S + s
                float cv = cosT[(size_t)row * D_ + d];
                float sv = sinT[(size_t)row * D_ + d];
#pragma unroll
                for (int p = 0; p < 2; ++p) {
                    float x1 = acc[m][p * 2 + 0][r], x2 = acc[m][p * 2 + 1][r];
                    unsigned short* o = Qo + (size_t)row * (NH_ * D_) + (hbase + p) * D_ + d;
                    o[0]  = f2bf((x1 * cv - x2 * sv) * QSCALE_);
                    o[64] = f2bf((x2 * cv + x1 * sv) * QSCALE_);
                }
            }
        }
    }
}

// =============== 128x128 2-phase bf16 GEMM for fused K+V (N=2048) ============
// A: Mx4096 bf16 (hs), B: 2048x4096 bf16 (stacked Wk,Wv). Grid 32x16 = 512
// blocks = 2/CU balanced; 64 KiB LDS -> 2 blocks/CU resident. 8 waves: wm=w>>2
// (64 rows), wn=w&3 owns n-frags {wn, wn+4} (cols wn*16, wn*16+64 -> RoPE pair
// thread-local). Chunks/K-tile: A(2 gll), B.h0(1), B.h1(1). Waits: P0 vmcnt(1),
// P1 vmcnt(3) (0 on last).  bn<1024: K RoPE epilogue; else V^T (B,NKV,D,S).
__global__ __launch_bounds__(512, 4) void gemm_kv_k(
    const unsigned short* __restrict__ A, const unsigned short* __restrict__ Bw,
    unsigned short* __restrict__ Ko, unsigned short* __restrict__ Vo,
    const float* __restrict__ cosT, const float* __restrict__ sinT,
    int M, int K)
{
    __shared__ __align__(16) unsigned short lds[32768];  // 64 KiB
    const int tid = threadIdx.x, lane = tid & 63;
    const int w = tid >> 6, wm = w >> 2, wn = w & 3;
    const int la = lane & 15, lb = lane >> 4;

    const int nwg = (int)gridDim.x;           // 512
    const int cpx = nwg >> 3;
    const int bid = (int)blockIdx.x;
    const int sw = (bid & 7) * cpx + (bid >> 3);
    const int ntn = 2048 >> 7;                // 16
    const int bm = (sw / ntn) << 7, bn = (sw % ntn) << 7;

    const int srow = tid >> 3;
    const int scol8 = (tid & 7) ^ (srow & 7);
    const size_t rK = (size_t)K;
    const unsigned short* gA = A + (size_t)(bm + srow) * rK + scol8 * 8;
    const unsigned short* gB = Bw + (size_t)(bn + srow) * rK + scol8 * 8;

#define KV_STG_A(buf, kt)  { gll16(gA + (size_t)(kt),          &lds[(buf)*8192 + tid*8]); \
                             gll16(gA + (size_t)(kt) + 64*rK,  &lds[(buf)*8192 + 4096 + tid*8]); }
#define KV_STG_B0(buf, kt)   gll16(gB + (size_t)(kt),          &lds[16384 + (buf)*8192 + tid*8])
#define KV_STG_B1(buf, kt)   gll16(gB + (size_t)(kt) + 64*rK,  &lds[16384 + (buf)*8192 + 4096 + tid*8])

    f32x4 acc[4][2];
#pragma unroll
    for (int m = 0; m < 4; ++m)
#pragma unroll
        for (int j = 0; j < 2; ++j) acc[m][j] = f32x4{0.f, 0.f, 0.f, 0.f};

    auto rdA = [&](int buf, int m, int kk) -> bf16x8 {
        int r = wm * 64 + m * 16 + la;
        int slot = (kk * 4 + lb) ^ (la & 7);
        return *(const bf16x8*)&lds[buf * 8192 + r * 64 + slot * 8];
    };
    auto rdB = [&](int buf, int j, int kk) -> bf16x8 {
        int r = (wn + 4 * j) * 16 + la;
        int slot = (kk * 4 + lb) ^ (la & 7);
        return *(const bf16x8*)&lds[16384 + buf * 8192 + r * 64 + slot * 8];
    };

    // prologue: issue order [A,A,B.h0,B.h1]
    KV_STG_A(0, 0); KV_STG_B0(0, 0); KV_STG_B1(0, 0);

    bf16x8 af[4][2], bf0[2], bf1[2];
    int cur = 0;
    const int nt = K >> 6;
    for (int t = 0; t < nt; ++t) {
        const bool pre = (t + 1 < nt);
        const int kn = (t + 1) << 6;
        const int nb = cur ^ 1;
        // P0: needs A + B.h0 of cur (first 3 outstanding); stages A+B.h0 of next
        asm volatile("s_waitcnt vmcnt(1)" ::: "memory");
        SB0(); __builtin_amdgcn_s_barrier(); SB0();
#pragma unroll
        for (int m = 0; m < 4; ++m)
#pragma unroll
            for (int kk = 0; kk < 2; ++kk) af[m][kk] = rdA(cur, m, kk);
#pragma unroll
        for (int kk = 0; kk < 2; ++kk) bf0[kk] = rdB(cur, 0, kk);
        if (pre) { KV_STG_A(nb, kn); KV_STG_B0(nb, kn); }
        __builtin_amdgcn_s_setprio(1);
#pragma unroll
        for (int kk = 0; kk < 2; ++kk)
#pragma unroll
            for (int m = 0; m < 4; ++m)
                acc[m][0] = mfma16(af[m][kk], bf0[kk], acc[m][0]);
        __builtin_amdgcn_s_setprio(0);
        // P1: needs B.h1 of cur; stages B.h1 of next
        if (pre) { asm volatile("s_waitcnt vmcnt(3)" ::: "memory"); }
        else     { asm volatile("s_waitcnt vmcnt(0)" ::: "memory"); }
        SB0(); __builtin_amdgcn_s_barrier(); SB0();
#pragma unroll
        for (int kk = 0; kk < 2; ++kk) bf1[kk] = rdB(cur, 1, kk);
        if (pre) KV_STG_B1(nb, kn);
        __builtin_amdgcn_s_setprio(1);
#pragma unroll
        for (int kk = 0; kk < 2; ++kk)
#pragma unroll
            for (int m = 0; m < 4; ++m)
                acc[m][1] = mfma16(af[m][kk], bf1[kk], acc[m][1]);
        __builtin_amdgcn_s_setprio(0);
        cur ^= 1;
    }
#undef KV_STG_A
#undef KV_STG_B0
#undef KV_STG_B1
#undef SB0

    const int rbase = bm + wm * 64;
    if (bn < 1024) {
        // K with RoPE (scale 1): j0 = d, j1 = d+64
        const int hbase = bn >> 7;
        const int d = wn * 16 + la;  // < 64
#pragma unroll
        for (int m = 0; m < 4; ++m)
#pragma unroll
            for (int r = 0; r < 4; ++r) {
                int row = rbase + m * 16 + lb * 4 + r;  // = b*S + s
                float cv = cosT[(size_t)row * D_ + d];
                float sv = sinT[(size_t)row * D_ + d];
                float x1 = acc[m][0][r], x2 = acc[m][1][r];
                unsigned short* o = Ko + (size_t)row * (NKV_ * D_) + hbase * D_ + d;
                o[0]  = f2bf(x1 * cv - x2 * sv);
                o[64] = f2bf(x2 * cv + x1 * sv);
            }
    } else {
        // V^T (B,NKV,D,S)
        const int kv = (bn - 1024) >> 7;
#pragma unroll
        for (int m = 0; m < 4; ++m) {
            int row = rbase + m * 16 + lb * 4;
            int b = row >> 11, s = row & (S_ - 1);
#pragma unroll
            for (int j = 0; j < 2; ++j) {
                int d = (wn + 4 * j) * 16 + la;
                s16x4 pk;
#pragma unroll
                for (int r = 0; r < 4; ++r) pk[r] = (short)f2bf(acc[m][j][r]);
                *(s16x4*)&Vo[((size_t)(b * NKV_ + kv) * D_ + d) * S_ + s] = pk;
            }
        }
    }
}

// ---------------- legacy fp32-input GEMM (ws fallback) -----------------------
template<int EPI, bool ABF16>
__global__ __launch_bounds__(256) void gemm_legacy_k(
    const void* __restrict__ Ap, const float* __restrict__ Bp,
    void* __restrict__ Cp, const float* __restrict__ cosT,
    const float* __restrict__ sinT, int M, int N, int K, float scale)
{
    constexpr int LDT = 40;
    __shared__ __align__(16) unsigned short Asm[128 * LDT];
    __shared__ __align__(16) unsigned short Bsm[128 * LDT];
    const int tid = threadIdx.x;
    const int lane = tid & 63;
    const int w = tid >> 6;
    const int la = lane & 15, lb = lane >> 4;
    const int ntn = N >> 7;
    const int bm = (int)(blockIdx.x / ntn) << 7;
    const int bn = (int)(blockIdx.x % ntn) << 7;

    f32x4 acc[2][8];
#pragma unroll
    for (int i = 0; i < 2; ++i)
#pragma unroll
        for (int j = 0; j < 8; ++j) acc[i][j] = f32x4{0.f, 0.f, 0.f, 0.f};

    for (int kt = 0; kt < K; kt += 32) {
        if constexpr (!ABF16) {
#pragma unroll
            for (int it = 0; it < 4; ++it) {
                int idx = it * 256 + tid;
                int r = idx >> 3, c = (idx & 7) << 2;
                const float* g = (const float*)Ap + (size_t)(bm + r) * K + kt + c;
                f32x4 v = *(const f32x4*)g;
                union { unsigned long long q; unsigned short u[4]; } pk;
                pk.u[0] = f2bf(v[0]); pk.u[1] = f2bf(v[1]);
                pk.u[2] = f2bf(v[2]); pk.u[3] = f2bf(v[3]);
                *(unsigned long long*)&Asm[r * LDT + c] = pk.q;
            }
        } else {
#pragma unroll
            for (int it = 0; it < 2; ++it) {
                int idx = it * 256 + tid;
                int r = idx >> 2, c = (idx & 3) << 3;
                const unsigned short* g =
                    (const unsigned short*)Ap + (size_t)(bm + r) * K + kt + c;
                *(bf16x8*)&Asm[r * LDT + c] = *(const bf16x8*)g;
            }
        }
#pragma unroll
        for (int it = 0; it < 4; ++it) {
            int idx = it * 256 + tid;
            int r = idx >> 3, c = (idx & 7) << 2;
            const float* g = Bp + (size_t)(bn + r) * K + kt + c;
            f32x4 v = *(const f32x4*)g;
            union { unsigned long long q; unsigned short u[4]; } pk;
            pk.u[0] = f2bf(v[0]); pk.u[1] = f2bf(v[1]);
            pk.u[2] = f2bf(v[2]); pk.u[3] = f2bf(v[3]);
            *(unsigned long long*)&Bsm[r * LDT + c] = pk.q;
        }
        __syncthreads();
        bf16x8 af0 = *(bf16x8*)&Asm[(w * 32 + la) * LDT + lb * 8];
        bf16x8 af1 = *(bf16x8*)&Asm[(w * 32 + 16 + la) * LDT + lb * 8];
#pragma unroll
        for (int nb = 0; nb < 8; ++nb) {
            bf16x8 bfr = *(bf16x8*)&Bsm[(nb * 16 + la) * LDT + lb * 8];
            acc[0][nb] = mfma16(af0, bfr, acc[0][nb]);
            acc[1][nb] = mfma16(af1, bfr, acc[1][nb]);
        }
        __syncthreads();
    }

    const int rbase = bm + w * 32;
    if constexpr (EPI == 0) {
        float* C = (float*)Cp;
#pragma unroll
        for (int mf = 0; mf < 2; ++mf)
#pragma unroll
            for (int nb = 0; nb < 8; ++nb)
#pragma unroll
                for (int r = 0; r < 4; ++r)
                    C[(size_t)(rbase + mf * 16 + lb * 4 + r) * N + bn + nb * 16 + la] =
                        acc[mf][nb][r];
    } else if constexpr (EPI == 1) {
        unsigned short* C = (unsigned short*)Cp;
#pragma unroll
        for (int mf = 0; mf < 2; ++mf) {
#pragma unroll
            for (int r = 0; r < 4; ++r) {
                int m = rbase + mf * 16 + lb * 4 + r;
                const float* cb = cosT + (size_t)m * D_;
                const float* sb = sinT + (size_t)m * D_;
#pragma unroll
                for (int nb = 0; nb < 4; ++nb) {
                    int d = nb * 16 + la;
                    float c = cb[d], s = sb[d];
                    float x1 = acc[mf][nb][r], x2 = acc[mf][nb + 4][r];
                    C[(size_t)m * N + bn + d]      = f2bf((x1 * c - x2 * s) * scale);
                    C[(size_t)m * N + bn + d + 64] = f2bf((x2 * c + x1 * s) * scale);
                }
            }
        }
    } else {
        unsigned short* C = (unsigned short*)Cp;
#pragma unroll
        for (int mf = 0; mf < 2; ++mf)
#pragma unroll
            for (int nb = 0; nb < 8; ++nb)
#pragma unroll
                for (int r = 0; r < 4; ++r) {
                    int m = rbase + mf * 16 + lb * 4 + r;
                    int b = m >> 11, s = m & (S_ - 1);
                    int n = bn + nb * 16 + la;
                    int kv = n >> 7, d = n & 127;
                    C[(((size_t)b * NKV_ + kv) * D_ + d) * S_ + s] =
                        f2bf(acc[mf][nb][r]);
                }
    }
}

// ---------------- flash attention: 4 waves x 32 q-rows, KVBLK=64 --------------
__global__ __launch_bounds__(256, 2) void attn2_k(
    const unsigned short* __restrict__ Qw,  // (B,S,NH,D) bf16 * QSCALE
    const unsigned short* __restrict__ Kw,  // (B,S,NKV,D) bf16
    const unsigned short* __restrict__ Vt,  // (B,NKV,D,S) bf16
    unsigned short* __restrict__ Ow)        // (B,S,NH*D) bf16
{
    constexpr int LDP = 72;
    __shared__ __align__(16) unsigned short Ksm[64 * 128];
    __shared__ __align__(16) unsigned short Vsm[128 * 64];
    __shared__ __align__(16) unsigned short Psm[4][32 * LDP];
    const int tid = threadIdx.x, lane = tid & 63, w = tid >> 6;
    const int la = lane & 15, lb = lane >> 4;
    const int blk = blockIdx.x;
    const int qbi = (S_ / 128 - 1) - (blk >> 6);  // heavy blocks first
    const int bh = blk & 63;
    const int b = bh >> 5, h = bh & 31;
    const int kvh = h >> 2;
    const int qb = qbi * 128;
    const int qw0 = qb + w * 32;

    bf16x8 fq[2][4];
    const unsigned short* qp =
        Qw + ((size_t)(b * S_ + qw0 + la) * NH_ + h) * D_ + lb * 8;
#pragma unroll
    for (int mq = 0; mq < 2; ++mq)
#pragma unroll
        for (int kc = 0; kc < 4; ++kc)
            fq[mq][kc] = *(const bf16x8*)(qp + (size_t)mq * 16 * NH_ * D_ + kc * 32);

    float m_[2], l_[2];
    f32x4 oacc[8][2];
    m_[0] = m_[1] = -__builtin_inff();
    l_[0] = l_[1] = 0.f;
#pragma unroll
    for (int db = 0; db < 8; ++db)
#pragma unroll
        for (int mq = 0; mq < 2; ++mq) oacc[db][mq] = f32x4{0.f, 0.f, 0.f, 0.f};

    const int ntiles = (qb + 128) >> 6;
    for (int t = 0; t < ntiles; ++t) {
        const int kv0 = t << 6;
        {
            const int rb = tid >> 4, sl = tid & 15;
#pragma unroll
            for (int it = 0; it < 4; ++it) {
                int row = it * 16 + rb;
                int cc = sl ^ (row & 7);
                const unsigned short* g =
                    Kw + ((size_t)(b * S_ + kv0 + row) * NKV_ + kvh) * D_ + cc * 8;
                gll16(g, &Ksm[(it * 256 + tid) * 8]);
            }
        }
        {
            const int rb = tid >> 3, sl = tid & 7;
#pragma unroll
            for (int it = 0; it < 4; ++it) {
                int row = it * 32 + rb;
                int cc = sl ^ (row & 7);
                const unsigned short* g =
                    Vt + ((size_t)(b * NKV_ + kvh) * D_ + row) * S_ + kv0 + cc * 8;
                gll16(g, &Vsm[(it * 256 + tid) * 8]);
            }
        }
        __syncthreads();

        if (kv0 < qw0 + 32) {
            f32x4 sacc[4][2];
#pragma unroll
            for (int nk = 0; nk < 4; ++nk)
#pragma unroll
                for (int mq = 0; mq < 2; ++mq) sacc[nk][mq] = f32x4{0.f, 0.f, 0.f, 0.f};
#pragma unroll
            for (int kc = 0; kc < 4; ++kc) {
#pragma unroll
                for (int nk = 0; nk < 4; ++nk) {
                    int row = nk * 16 + la;
                    int slot = (kc * 4 + lb) ^ (la & 7);
                    bf16x8 fk = *(const bf16x8*)&Ksm[row * 128 + slot * 8];
#pragma unroll
                    for (int mq = 0; mq < 2; ++mq)
                        sacc[nk][mq] = mfma16(fk, fq[mq][kc], sacc[nk][mq]);
                }
            }
            const bool diag = (kv0 + 63 > qw0);  // wave-uniform: tile touches diagonal
            float pv[4][2][4];
            float pm[2];
#pragma unroll
            for (int mq = 0; mq < 2; ++mq) {
                int q = qw0 + mq * 16 + la;
                float mx = -__builtin_inff();
#pragma unroll
                for (int nk = 0; nk < 4; ++nk)
#pragma unroll
                    for (int r = 0; r < 4; ++r) {
                        float s = sacc[nk][mq][r];
                        if (diag) {
                            int k = kv0 + nk * 16 + lb * 4 + r;
                            s = (k <= q) ? s : -__builtin_inff();
                        }
                        pv[nk][mq][r] = s;
                        mx = fmaxf(mx, s);
                    }
                mx = fmaxf(mx, __shfl_xor(mx, 16));
                mx = fmaxf(mx, __shfl_xor(mx, 32));
                pm[mq] = mx;
            }
            // T13 defer-rescale: skip when no lane exceeds running max by >8
            // (log2 domain: P <= 2^8, exact algebra, bf16-safe)
            const bool upd =
                __any((pm[0] > m_[0] + 8.f) || (pm[1] > m_[1] + 8.f));
            if (upd) {
#pragma unroll
                for (int mq = 0; mq < 2; ++mq) {
                    float mn = fmaxf(m_[mq], pm[mq]);
                    float fac = exp2f(m_[mq] - mn);
                    m_[mq] = mn;
                    l_[mq] *= fac;
#pragma unroll
                    for (int db = 0; db < 8; ++db) oacc[db][mq] *= fac;
                }
            }
            float tsum[2] = {0.f, 0.f};
#pragma unroll
            for (int nk = 0; nk < 4; ++nk)
#pragma unroll
                for (int mq = 0; mq < 2; ++mq)
#pragma unroll
                    for (int r = 0; r < 4; ++r) {
                        float p = exp2f(pv[nk][mq][r] - m_[mq]);
                        pv[nk][mq][r] = p;
                        tsum[mq] += p;
                    }
#pragma unroll
            for (int mq = 0; mq < 2; ++mq) {
                float s = tsum[mq];
                s += __shfl_xor(s, 16);
                s += __shfl_xor(s, 32);
                l_[mq] += s;
            }

            unsigned short* pp = &Psm[w][0];
#pragma unroll
            for (int nk = 0; nk < 4; ++nk)
#pragma unroll
                for (int mq = 0; mq < 2; ++mq) {
                    s16x4 pk;
#pragma unroll
                    for (int r = 0; r < 4; ++r) pk[r] = (short)f2bf(pv[nk][mq][r]);
                    *(s16x4*)&pp[(mq * 16 + la) * LDP + nk * 16 + lb * 4] = pk;
                }
            bf16x8 fp[2][2];
#pragma unroll
            for (int mq = 0; mq < 2; ++mq)
#pragma unroll
                for (int ks = 0; ks < 2; ++ks)
                    fp[mq][ks] =
                        *(const bf16x8*)&pp[(mq * 16 + la) * LDP + ks * 32 + lb * 8];
#pragma unroll
            for (int ks = 0; ks < 2; ++ks)
#pragma unroll
                for (int db = 0; db < 8; ++db) {
                    int row = db * 16 + la;
                    int slot = (ks * 4 + lb) ^ (la & 7);
                    bf16x8 fv = *(const bf16x8*)&Vsm[row * 64 + slot * 8];
#pragma unroll
                    for (int mq = 0; mq < 2; ++mq)
                        oacc[db][mq] = mfma16(fv, fp[mq][ks], oacc[db][mq]);
                }
        }
        __syncthreads();
    }

#pragma unroll
    for (int mq = 0; mq < 2; ++mq) {
        float rl = 1.f / l_[mq];
        int q = qw0 + mq * 16 + la;
#pragma unroll
        for (int db = 0; db < 8; ++db) {
            f32x4 o = oacc[db][mq];
            s16x4 pk;
#pragma unroll
            for (int r = 0; r < 4; ++r) pk[r] = (short)f2bf(o[r] * rl);
            int d = db * 16 + lb * 4;
            *(s16x4*)(Ow + (size_t)(b * S_ + q) * (NH_ * D_) + h * D_ + d) = pk;
        }
    }
}

extern "C" void kernel_launch(void* const* d_in, const int* in_sizes, int n_in,
                              void* d_out, int out_size, void* d_ws, size_t ws_size,
                              hipStream_t stream) {
    const float* hs   = (const float*)d_in[0];
    const float* cosT = (const float*)d_in[1];
    const float* sinT = (const float*)d_in[2];
    const float* Wq   = (const float*)d_in[3];
    const float* Wk   = (const float*)d_in[4];
    const float* Wv   = (const float*)d_in[5];
    const float* Wo   = (const float*)d_in[6];

    constexpr size_t Qn  = (size_t)B_ * S_ * NH_ * D_;    // 16.77M
    constexpr size_t Kn  = (size_t)B_ * S_ * NKV_ * D_;   // 4.19M
    constexpr size_t Hn  = (size_t)B_ * S_ * HID_;        // 16.77M
    constexpr size_t Wqn = (size_t)NH_ * D_ * HID_;       // 16.77M
    constexpr size_t Wkn = (size_t)NKV_ * D_ * HID_;      // 4.19M

    unsigned short* Qws   = (unsigned short*)d_ws;
    unsigned short* Kws   = Qws + Qn;
    unsigned short* Vtws  = Kws + Kn;
    unsigned short* AOws  = Vtws + Kn;
    unsigned short* hsb   = AOws + Qn;
    unsigned short* Wqkvb = hsb + Hn;                  // stacked (6144, 4096)
    unsigned short* Wob   = Wqkvb + Wqn + 2 * Wkn;
    constexpr size_t need = (Qn + 2 * Kn + Qn + Hn + Wqn + 2 * Wkn + Wqn) * 2;

    const int M = B_ * S_;
    dim3 blk(256);

    if (ws_size >= need) {
        // one merged cast launch: hs, Wq, Wk, Wv, Wo -> bf16
        cast_all_k<<<dim3(28672), blk, 0, stream>>>(
            hs, Wq, Wk, Wv, Wo,
            hsb, Wqkvb, Wqkvb + Wqn, Wqkvb + Wqn + Wkn, Wob);

        // Q = rope(hs @ Wq^T) * QSCALE  (grid 16x16 = 256, balanced)
        gemm256_k<1><<<dim3((M / 256) * (HID_ / 256)), dim3(512), 0, stream>>>(
            hsb, Wqkvb, nullptr, Qws, cosT, sinT, M, HID_, HID_);
        // K = rope(hs @ Wk^T), V^T = (hs @ Wv^T)^T  (grid 32x16 = 512 = 2/CU)
        gemm_kv_k<<<dim3((M / 128) * (2048 / 128)), dim3(512), 0, stream>>>(
            hsb, Wqkvb + Wqn, Kws, Vtws, cosT, sinT, M, HID_);
        attn2_k<<<dim3(B_ * NH_ * (S_ / 128)), blk, 0, stream>>>(Qws, Kws, Vtws, AOws);
        // out = AO @ Wo^T (f32 epilogue)
        gemm256_k<0><<<dim3((M / 256) * (HID_ / 256)), dim3(512), 0, stream>>>(
            AOws, Wob, (float*)d_out, nullptr, nullptr, nullptr, M, HID_, NH_ * D_);
    } else {
        // fallback: fp32-staging GEMMs + attention
        unsigned short* Qf = (unsigned short*)d_ws;
        unsigned short* Kf = Qf + Qn;
        unsigned short* Vf = Kf + Kn;
        unsigned short* AOf = Vf + Kn;
        gemm_legacy_k<1, false><<<dim3((M / 128) * (NH_ * D_ / 128)), blk, 0, stream>>>(
            hs, Wq, Qf, cosT, sinT, M, NH_ * D_, HID_, QSCALE_);
        gemm_legacy_k<1, false><<<dim3((M / 128) * (NKV_ * D_ / 128)), blk, 0, stream>>>(
            hs, Wk, Kf, cosT, sinT, M, NKV_ * D_, HID_, 1.0f);
        gemm_legacy_k<3, false><<<dim3((M / 128) * (NKV_ * D_ / 128)), blk, 0, stream>>>(
            hs, Wv, Vf, nullptr, nullptr, M, NKV_ * D_, HID_, 0.f);
        attn2_k<<<dim3(B_ * NH_ * (S_ / 128)), blk, 0, stream>>>(Qf, Kf, Vf, AOf);
        gemm_legacy_k<0, true><<<dim3((M / 128) * (HID_ / 128)), blk, 0, stream>>>(
            AOf, Wo, (float*)d_out, nullptr, nullptr, M, HID_, NH_ * D_, 0.f);
    }
}

// Round 5
// 474.243 us; speedup vs baseline: 4.1808x; 1.0110x over previous
//
#include <hip/hip_runtime.h>
#include <hip/hip_bf16.h>

#define DEV __device__ __forceinline__

typedef __attribute__((ext_vector_type(8))) short bf16x8;
typedef __attribute__((ext_vector_type(4))) short s16x4;
typedef __attribute__((ext_vector_type(4))) float f32x4;

constexpr int B_ = 2, S_ = 2048, HID_ = 4096, NH_ = 32, NKV_ = 8, D_ = 128;
constexpr int GROUPS_ = NH_ / NKV_;
// fold 1/sqrt(D) and log2(e) into Q so attention uses exp2 directly
constexpr float QSCALE_ = 0.08838834764831845f * 1.4426950408889634f;

DEV unsigned short f2bf(float x) {
    union { float f; unsigned int u; } v; v.f = x;
    unsigned int r = v.u + 0x7fffu + ((v.u >> 16) & 1u);
    return (unsigned short)(r >> 16);
}

DEV f32x4 mfma16(bf16x8 a, bf16x8 b, f32x4 c) {
    return __builtin_amdgcn_mfma_f32_16x16x32_bf16(a, b, c, 0, 0, 0);
}

DEV void gll16(const void* g, void* l) {
    __builtin_amdgcn_global_load_lds(
        (const __attribute__((address_space(1))) unsigned int*)g,
        (__attribute__((address_space(3))) unsigned int*)l, 16, 0, 0);
}

// ---------------- merged fp32 -> bf16 cast (one launch, 5 segments) ----------
__global__ __launch_bounds__(256) void cast_all_k(
    const float* __restrict__ s0, const float* __restrict__ s1,
    const float* __restrict__ s2, const float* __restrict__ s3,
    const float* __restrict__ s4,
    unsigned short* __restrict__ d0, unsigned short* __restrict__ d1,
    unsigned short* __restrict__ d2, unsigned short* __restrict__ d3,
    unsigned short* __restrict__ d4)
{
    int bb = blockIdx.x;
    const float* s; unsigned short* d; int off;
    if      (bb < 8192)  { s = s0; d = d0; off = bb; }
    else if (bb < 16384) { s = s1; d = d1; off = bb - 8192; }
    else if (bb < 18432) { s = s2; d = d2; off = bb - 16384; }
    else if (bb < 20480) { s = s3; d = d3; off = bb - 18432; }
    else                 { s = s4; d = d4; off = bb - 20480; }
    size_t i = ((size_t)off * 256 + threadIdx.x) * 8;
    const f32x4* sp = (const f32x4*)(s + i);
    f32x4 a = sp[0], b = sp[1];
    bf16x8 o;
    o[0] = (short)f2bf(a[0]); o[1] = (short)f2bf(a[1]);
    o[2] = (short)f2bf(a[2]); o[3] = (short)f2bf(a[3]);
    o[4] = (short)f2bf(b[0]); o[5] = (short)f2bf(b[1]);
    o[6] = (short)f2bf(b[2]); o[7] = (short)f2bf(b[3]);
    *(bf16x8*)(d + i) = o;
}

// =============== 256x256 8-phase bf16 GEMM (T2+T3+T4+T5), C = A @ B^T ========
// EPI 0: f32 row-major store. EPI 1: Q RoPE epilogue (N=4096 launch).
template<int EPI>
__global__ __launch_bounds__(512, 2) void gemm256_k(
    const unsigned short* __restrict__ A, const unsigned short* __restrict__ Bw,
    float* __restrict__ Cf, unsigned short* __restrict__ Qo,
    const float* __restrict__ cosT, const float* __restrict__ sinT,
    int M, int N, int K)
{
    __shared__ __align__(16) unsigned short lds[65536];  // 128 KiB
    const int tid = threadIdx.x, lane = tid & 63;
    const int w = tid >> 6, wm = w >> 2, wn = w & 3;
    const int la = lane & 15, lb = lane >> 4;

    const int nwg = (int)gridDim.x;
    const int cpx = nwg >> 3;
    const int bid = (int)blockIdx.x;
    const int sw = (bid & 7) * cpx + (bid >> 3);
    const int ntn = N >> 8;
    const int bm = (sw / ntn) << 8, bn = (sw % ntn) << 8;

    const int srow = tid >> 3;                       // 0..63
    const int scol8 = (tid & 7) ^ (srow & 7);        // involution
    const size_t rK = (size_t)K;
    const unsigned short* gA = A + (size_t)(bm + srow) * rK + scol8 * 8;
    const unsigned short* gB = Bw + (size_t)(bn + srow) * rK + scol8 * 8;

#define STAGE_A_H0(buf, kt) { gll16(gA + (size_t)(kt),            &lds[(buf)*16384 + tid*8]); \
                              gll16(gA + (size_t)(kt) + 128*rK,   &lds[(buf)*16384 + 8192 + tid*8]); }
#define STAGE_A_H1(buf, kt) { gll16(gA + (size_t)(kt) + 64*rK,    &lds[(buf)*16384 + 4096 + tid*8]); \
                              gll16(gA + (size_t)(kt) + 192*rK,   &lds[(buf)*16384 + 12288 + tid*8]); }
#define STAGE_B_H0(buf, kt) { gll16(gB + (size_t)(kt),            &lds[32768 + (buf)*16384 + tid*8]); \
                              gll16(gB + (size_t)(kt) + 64*rK,    &lds[32768 + (buf)*16384 + 4096 + tid*8]); }
#define STAGE_B_H1(buf, kt) { gll16(gB + (size_t)(kt) + 128*rK,   &lds[32768 + (buf)*16384 + 8192 + tid*8]); \
                              gll16(gB + (size_t)(kt) + 192*rK,   &lds[32768 + (buf)*16384 + 12288 + tid*8]); }
#define SB0() __builtin_amdgcn_sched_barrier(0)

    f32x4 acc[8][4];
#pragma unroll
    for (int m = 0; m < 8; ++m)
#pragma unroll
        for (int j = 0; j < 4; ++j) acc[m][j] = f32x4{0.f, 0.f, 0.f, 0.f};

    auto rdA = [&](int buf, int m, int kk) -> bf16x8 {
        int r = wm * 128 + m * 16 + la;
        int slot = (kk * 4 + lb) ^ (la & 7);
        return *(const bf16x8*)&lds[buf * 16384 + r * 64 + slot * 8];
    };
    auto rdB = [&](int buf, int j, int kk) -> bf16x8 {
        int r = (wn + 4 * j) * 16 + la;
        int slot = (kk * 4 + lb) ^ (la & 7);
        return *(const bf16x8*)&lds[32768 + buf * 16384 + r * 64 + slot * 8];
    };

    STAGE_A_H0(0, 0); STAGE_B_H0(0, 0); STAGE_B_H1(0, 0); STAGE_A_H1(0, 0);

    bf16x8 af[4][2], b01[2][2], b23[2][2];
    int cur = 0;
    const int nt = K >> 6;
    for (int t = 0; t < nt; ++t) {
        const bool pre = (t + 1 < nt);
        const int kn = (t + 1) << 6;
        const int nb = cur ^ 1;
        // P0
        asm volatile("s_waitcnt vmcnt(2)" ::: "memory");
        SB0(); __builtin_amdgcn_s_barrier(); SB0();
#pragma unroll
        for (int m = 0; m < 4; ++m)
#pragma unroll
            for (int kk = 0; kk < 2; ++kk) af[m][kk] = rdA(cur, m, kk);
#pragma unroll
        for (int j = 0; j < 2; ++j)
#pragma unroll
            for (int kk = 0; kk < 2; ++kk) b01[j][kk] = rdB(cur, j, kk);
        if (pre) STAGE_A_H0(nb, kn);
        __builtin_amdgcn_s_setprio(1);
#pragma unroll
        for (int kk = 0; kk < 2; ++kk)
#pragma unroll
            for (int m = 0; m < 4; ++m)
#pragma unroll
                for (int j = 0; j < 2; ++j)
                    acc[m][j] = mfma16(af[m][kk], b01[j][kk], acc[m][j]);
        __builtin_amdgcn_s_setprio(0);
        // P1
        SB0(); __builtin_amdgcn_s_barrier(); SB0();
#pragma unroll
        for (int j = 0; j < 2; ++j)
#pragma unroll
            for (int kk = 0; kk < 2; ++kk) b23[j][kk] = rdB(cur, j + 2, kk);
        if (pre) STAGE_B_H0(nb, kn);
        __builtin_amdgcn_s_setprio(1);
#pragma unroll
        for (int kk = 0; kk < 2; ++kk)
#pragma unroll
            for (int m = 0; m < 4; ++m)
#pragma unroll
                for (int j = 0; j < 2; ++j)
                    acc[m][j + 2] = mfma16(af[m][kk], b23[j][kk], acc[m][j + 2]);
        __builtin_amdgcn_s_setprio(0);
        // P2
        if (pre) { asm volatile("s_waitcnt vmcnt(4)" ::: "memory"); }
        else     { asm volatile("s_waitcnt vmcnt(0)" ::: "memory"); }
        SB0(); __builtin_amdgcn_s_barrier(); SB0();
#pragma unroll
        for (int m = 0; m < 4; ++m)
#pragma unroll
            for (int kk = 0; kk < 2; ++kk) af[m][kk] = rdA(cur, m + 4, kk);
        if (pre) STAGE_B_H1(nb, kn);
        __builtin_amdgcn_s_setprio(1);
#pragma unroll
        for (int kk = 0; kk < 2; ++kk)
#pragma unroll
            for (int m = 0; m < 4; ++m)
#pragma unroll
                for (int j = 0; j < 2; ++j)
                    acc[m + 4][j + 2] = mfma16(af[m][kk], b23[j][kk], acc[m + 4][j + 2]);
        __builtin_amdgcn_s_setprio(0);
        // P3
        SB0(); __builtin_amdgcn_s_barrier(); SB0();
        if (pre) STAGE_A_H1(nb, kn);
        __builtin_amdgcn_s_setprio(1);
#pragma unroll
        for (int kk = 0; kk < 2; ++kk)
#pragma unroll
            for (int m = 0; m < 4; ++m)
#pragma unroll
                for (int j = 0; j < 2; ++j)
                    acc[m + 4][j] = mfma16(af[m][kk], b01[j][kk], acc[m + 4][j]);
        __builtin_amdgcn_s_setprio(0);
        cur ^= 1;
    }
#undef STAGE_A_H0
#undef STAGE_A_H1
#undef STAGE_B_H0
#undef STAGE_B_H1

    const int srow0 = bm + wm * 128;
    if constexpr (EPI == 0) {
#pragma unroll
        for (int m = 0; m < 8; ++m)
#pragma unroll
            for (int j = 0; j < 4; ++j) {
                int col = bn + (wn + 4 * j) * 16 + la;
#pragma unroll
                for (int r = 0; r < 4; ++r)
                    Cf[(size_t)(srow0 + m * 16 + lb * 4 + r) * N + col] = acc[m][j][r];
            }
    } else {
        // Q RoPE: j0/j1 = head hbase, j2/j3 = head hbase+1
        const int hbase = bn >> 7;
        const int d = wn * 16 + la;  // < 64; cos[d]==cos[d+64]
#pragma unroll
        for (int m = 0; m < 8; ++m) {
#pragma unroll
            for (int r = 0; r < 4; ++r) {
                int row = srow0 + m * 16 + lb * 4 + r;  // = b*S + s
                float cv = cosT[(size_t)row * D_ + d];
                float sv = sinT[(size_t)row * D_ + d];
#pragma unroll
                for (int p = 0; p < 2; ++p) {
                    float x1 = acc[m][p * 2 + 0][r], x2 = acc[m][p * 2 + 1][r];
                    unsigned short* o = Qo + (size_t)row * (NH_ * D_) + (hbase + p) * D_ + d;
                    o[0]  = f2bf((x1 * cv - x2 * sv) * QSCALE_);
                    o[64] = f2bf((x2 * cv + x1 * sv) * QSCALE_);
                }
            }
        }
    }
}

// =============== 128x128 2-phase bf16 GEMM for fused K+V (N=2048) ============
__global__ __launch_bounds__(512, 4) void gemm_kv_k(
    const unsigned short* __restrict__ A, const unsigned short* __restrict__ Bw,
    unsigned short* __restrict__ Ko, unsigned short* __restrict__ Vo,
    const float* __restrict__ cosT, const float* __restrict__ sinT,
    int M, int K)
{
    __shared__ __align__(16) unsigned short lds[32768];  // 64 KiB
    const int tid = threadIdx.x, lane = tid & 63;
    const int w = tid >> 6, wm = w >> 2, wn = w & 3;
    const int la = lane & 15, lb = lane >> 4;

    const int nwg = (int)gridDim.x;           // 512
    const int cpx = nwg >> 3;
    const int bid = (int)blockIdx.x;
    const int sw = (bid & 7) * cpx + (bid >> 3);
    const int ntn = 2048 >> 7;                // 16
    const int bm = (sw / ntn) << 7, bn = (sw % ntn) << 7;

    const int srow = tid >> 3;
    const int scol8 = (tid & 7) ^ (srow & 7);
    const size_t rK = (size_t)K;
    const unsigned short* gA = A + (size_t)(bm + srow) * rK + scol8 * 8;
    const unsigned short* gB = Bw + (size_t)(bn + srow) * rK + scol8 * 8;

#define KV_STG_A(buf, kt)  { gll16(gA + (size_t)(kt),          &lds[(buf)*8192 + tid*8]); \
                             gll16(gA + (size_t)(kt) + 64*rK,  &lds[(buf)*8192 + 4096 + tid*8]); }
#define KV_STG_B0(buf, kt)   gll16(gB + (size_t)(kt),          &lds[16384 + (buf)*8192 + tid*8])
#define KV_STG_B1(buf, kt)   gll16(gB + (size_t)(kt) + 64*rK,  &lds[16384 + (buf)*8192 + 4096 + tid*8])
#define SB0() __builtin_amdgcn_sched_barrier(0)

    f32x4 acc[4][2];
#pragma unroll
    for (int m = 0; m < 4; ++m)
#pragma unroll
        for (int j = 0; j < 2; ++j) acc[m][j] = f32x4{0.f, 0.f, 0.f, 0.f};

    auto rdA = [&](int buf, int m, int kk) -> bf16x8 {
        int r = wm * 64 + m * 16 + la;
        int slot = (kk * 4 + lb) ^ (la & 7);
        return *(const bf16x8*)&lds[buf * 8192 + r * 64 + slot * 8];
    };
    auto rdB = [&](int buf, int j, int kk) -> bf16x8 {
        int r = (wn + 4 * j) * 16 + la;
        int slot = (kk * 4 + lb) ^ (la & 7);
        return *(const bf16x8*)&lds[16384 + buf * 8192 + r * 64 + slot * 8];
    };

    KV_STG_A(0, 0); KV_STG_B0(0, 0); KV_STG_B1(0, 0);

    bf16x8 af[4][2], bf0[2], bf1[2];
    int cur = 0;
    const int nt = K >> 6;
    for (int t = 0; t < nt; ++t) {
        const bool pre = (t + 1 < nt);
        const int kn = (t + 1) << 6;
        const int nb = cur ^ 1;
        asm volatile("s_waitcnt vmcnt(1)" ::: "memory");
        SB0(); __builtin_amdgcn_s_barrier(); SB0();
#pragma unroll
        for (int m = 0; m < 4; ++m)
#pragma unroll
            for (int kk = 0; kk < 2; ++kk) af[m][kk] = rdA(cur, m, kk);
#pragma unroll
        for (int kk = 0; kk < 2; ++kk) bf0[kk] = rdB(cur, 0, kk);
        if (pre) { KV_STG_A(nb, kn); KV_STG_B0(nb, kn); }
        __builtin_amdgcn_s_setprio(1);
#pragma unroll
        for (int kk = 0; kk < 2; ++kk)
#pragma unroll
            for (int m = 0; m < 4; ++m)
                acc[m][0] = mfma16(af[m][kk], bf0[kk], acc[m][0]);
        __builtin_amdgcn_s_setprio(0);
        if (pre) { asm volatile("s_waitcnt vmcnt(3)" ::: "memory"); }
        else     { asm volatile("s_waitcnt vmcnt(0)" ::: "memory"); }
        SB0(); __builtin_amdgcn_s_barrier(); SB0();
#pragma unroll
        for (int kk = 0; kk < 2; ++kk) bf1[kk] = rdB(cur, 1, kk);
        if (pre) KV_STG_B1(nb, kn);
        __builtin_amdgcn_s_setprio(1);
#pragma unroll
        for (int kk = 0; kk < 2; ++kk)
#pragma unroll
            for (int m = 0; m < 4; ++m)
                acc[m][1] = mfma16(af[m][kk], bf1[kk], acc[m][1]);
        __builtin_amdgcn_s_setprio(0);
        cur ^= 1;
    }
#undef KV_STG_A
#undef KV_STG_B0
#undef KV_STG_B1
#undef SB0

    const int rbase = bm + wm * 64;
    if (bn < 1024) {
        const int hbase = bn >> 7;
        const int d = wn * 16 + la;  // < 64
#pragma unroll
        for (int m = 0; m < 4; ++m)
#pragma unroll
            for (int r = 0; r < 4; ++r) {
                int row = rbase + m * 16 + lb * 4 + r;  // = b*S + s
                float cv = cosT[(size_t)row * D_ + d];
                float sv = sinT[(size_t)row * D_ + d];
                float x1 = acc[m][0][r], x2 = acc[m][1][r];
                unsigned short* o = Ko + (size_t)row * (NKV_ * D_) + hbase * D_ + d;
                o[0]  = f2bf(x1 * cv - x2 * sv);
                o[64] = f2bf(x2 * cv + x1 * sv);
            }
    } else {
        const int kv = (bn - 1024) >> 7;
#pragma unroll
        for (int m = 0; m < 4; ++m) {
            int row = rbase + m * 16 + lb * 4;
            int b = row >> 11, s = row & (S_ - 1);
#pragma unroll
            for (int j = 0; j < 2; ++j) {
                int d = (wn + 4 * j) * 16 + la;
                s16x4 pk;
#pragma unroll
                for (int r = 0; r < 4; ++r) pk[r] = (short)f2bf(acc[m][j][r]);
                *(s16x4*)&Vo[((size_t)(b * NKV_ + kv) * D_ + d) * S_ + s] = pk;
            }
        }
    }
}

// ---------------- legacy fp32-input GEMM (ws fallback) -----------------------
template<int EPI, bool ABF16>
__global__ __launch_bounds__(256) void gemm_legacy_k(
    const void* __restrict__ Ap, const float* __restrict__ Bp,
    void* __restrict__ Cp, const float* __restrict__ cosT,
    const float* __restrict__ sinT, int M, int N, int K, float scale)
{
    constexpr int LDT = 40;
    __shared__ __align__(16) unsigned short Asm[128 * LDT];
    __shared__ __align__(16) unsigned short Bsm[128 * LDT];
    const int tid = threadIdx.x;
    const int lane = tid & 63;
    const int w = tid >> 6;
    const int la = lane & 15, lb = lane >> 4;
    const int ntn = N >> 7;
    const int bm = (int)(blockIdx.x / ntn) << 7;
    const int bn = (int)(blockIdx.x % ntn) << 7;

    f32x4 acc[2][8];
#pragma unroll
    for (int i = 0; i < 2; ++i)
#pragma unroll
        for (int j = 0; j < 8; ++j) acc[i][j] = f32x4{0.f, 0.f, 0.f, 0.f};

    for (int kt = 0; kt < K; kt += 32) {
        if constexpr (!ABF16) {
#pragma unroll
            for (int it = 0; it < 4; ++it) {
                int idx = it * 256 + tid;
                int r = idx >> 3, c = (idx & 7) << 2;
                const float* g = (const float*)Ap + (size_t)(bm + r) * K + kt + c;
                f32x4 v = *(const f32x4*)g;
                union { unsigned long long q; unsigned short u[4]; } pk;
                pk.u[0] = f2bf(v[0]); pk.u[1] = f2bf(v[1]);
                pk.u[2] = f2bf(v[2]); pk.u[3] = f2bf(v[3]);
                *(unsigned long long*)&Asm[r * LDT + c] = pk.q;
            }
        } else {
#pragma unroll
            for (int it = 0; it < 2; ++it) {
                int idx = it * 256 + tid;
                int r = idx >> 2, c = (idx & 3) << 3;
                const unsigned short* g =
                    (const unsigned short*)Ap + (size_t)(bm + r) * K + kt + c;
                *(bf16x8*)&Asm[r * LDT + c] = *(const bf16x8*)g;
            }
        }
#pragma unroll
        for (int it = 0; it < 4; ++it) {
            int idx = it * 256 + tid;
            int r = idx >> 3, c = (idx & 7) << 2;
            const float* g = Bp + (size_t)(bn + r) * K + kt + c;
            f32x4 v = *(const f32x4*)g;
            union { unsigned long long q; unsigned short u[4]; } pk;
            pk.u[0] = f2bf(v[0]); pk.u[1] = f2bf(v[1]);
            pk.u[2] = f2bf(v[2]); pk.u[3] = f2bf(v[3]);
            *(unsigned long long*)&Bsm[r * LDT + c] = pk.q;
        }
        __syncthreads();
        bf16x8 af0 = *(bf16x8*)&Asm[(w * 32 + la) * LDT + lb * 8];
        bf16x8 af1 = *(bf16x8*)&Asm[(w * 32 + 16 + la) * LDT + lb * 8];
#pragma unroll
        for (int nb = 0; nb < 8; ++nb) {
            bf16x8 bfr = *(bf16x8*)&Bsm[(nb * 16 + la) * LDT + lb * 8];
            acc[0][nb] = mfma16(af0, bfr, acc[0][nb]);
            acc[1][nb] = mfma16(af1, bfr, acc[1][nb]);
        }
        __syncthreads();
    }

    const int rbase = bm + w * 32;
    if constexpr (EPI == 0) {
        float* C = (float*)Cp;
#pragma unroll
        for (int mf = 0; mf < 2; ++mf)
#pragma unroll
            for (int nb = 0; nb < 8; ++nb)
#pragma unroll
                for (int r = 0; r < 4; ++r)
                    C[(size_t)(rbase + mf * 16 + lb * 4 + r) * N + bn + nb * 16 + la] =
                        acc[mf][nb][r];
    } else if constexpr (EPI == 1) {
        unsigned short* C = (unsigned short*)Cp;
#pragma unroll
        for (int mf = 0; mf < 2; ++mf) {
#pragma unroll
            for (int r = 0; r < 4; ++r) {
                int m = rbase + mf * 16 + lb * 4 + r;
                const float* cb = cosT + (size_t)m * D_;
                const float* sb = sinT + (size_t)m * D_;
#pragma unroll
                for (int nb = 0; nb < 4; ++nb) {
                    int d = nb * 16 + la;
                    float c = cb[d], s = sb[d];
                    float x1 = acc[mf][nb][r], x2 = acc[mf][nb + 4][r];
                    C[(size_t)m * N + bn + d]      = f2bf((x1 * c - x2 * s) * scale);
                    C[(size_t)m * N + bn + d + 64] = f2bf((x2 * c + x1 * s) * scale);
                }
            }
        }
    } else {
        unsigned short* C = (unsigned short*)Cp;
#pragma unroll
        for (int mf = 0; mf < 2; ++mf)
#pragma unroll
            for (int nb = 0; nb < 8; ++nb)
#pragma unroll
                for (int r = 0; r < 4; ++r) {
                    int m = rbase + mf * 16 + lb * 4 + r;
                    int b = m >> 11, s = m & (S_ - 1);
                    int n = bn + nb * 16 + la;
                    int kv = n >> 7, d = n & 127;
                    C[(((size_t)b * NKV_ + kv) * D_ + d) * S_ + s] =
                        f2bf(acc[mf][nb][r]);
                }
    }
}

// ========== flash attention v3: dbuf K/V, register-resident P ================
// 4 waves x 32 q-rows, KVBLK=64, double-buffered LDS (64 KiB), counted vmcnt.
// Swapped QK^T: lane-local pv[nk][mq][r] = P[q=mq*16+la][k=kv0+nk*16+lb*4+r].
// PV uses k-slot permutation sigma(lb*8+m*4+r) = ks*32+m*16+lb*4+r applied to
// BOTH operands -> P fragment is pure lane-local cvt_pk; V fragment = 2x b64.
__global__ __launch_bounds__(256, 2) void attn3_k(
    const unsigned short* __restrict__ Qw,  // (B,S,NH,D) bf16 * QSCALE
    const unsigned short* __restrict__ Kw,  // (B,S,NKV,D) bf16
    const unsigned short* __restrict__ Vt,  // (B,NKV,D,S) bf16
    unsigned short* __restrict__ Ow)        // (B,S,NH*D) bf16
{
    __shared__ __align__(16) unsigned short Ksm[2][64 * 128];   // 2 x 16 KiB
    __shared__ __align__(16) unsigned short Vsm[2][128 * 64];   // 2 x 16 KiB
    const int tid = threadIdx.x, lane = tid & 63, w = tid >> 6;
    const int la = lane & 15, lb = lane >> 4;
    const int blk = blockIdx.x;
    const int qbi = (S_ / 128 - 1) - (blk >> 6);  // heavy blocks first
    const int bh = blk & 63;
    const int b = bh >> 5, h = bh & 31;
    const int kvh = h >> 2;
    const int qb = qbi * 128;
    const int qw0 = qb + w * 32;

    bf16x8 fq[2][4];
    const unsigned short* qp =
        Qw + ((size_t)(b * S_ + qw0 + la) * NH_ + h) * D_ + lb * 8;
#pragma unroll
    for (int mq = 0; mq < 2; ++mq)
#pragma unroll
        for (int kc = 0; kc < 4; ++kc)
            fq[mq][kc] = *(const bf16x8*)(qp + (size_t)mq * 16 * NH_ * D_ + kc * 32);

    float m_[2], l_[2];
    f32x4 oacc[8][2];
    m_[0] = m_[1] = -__builtin_inff();
    l_[0] = l_[1] = 0.f;
#pragma unroll
    for (int db = 0; db < 8; ++db)
#pragma unroll
        for (int mq = 0; mq < 2; ++mq) oacc[db][mq] = f32x4{0.f, 0.f, 0.f, 0.f};

    // staging (4 gll each; inverse-swizzled global source, linear LDS dest)
    const int krb = tid >> 4, ksl = tid & 15;
    const int vrb = tid >> 3, vsl = tid & 7;
    const unsigned short* kbase = Kw + ((size_t)b * S_ * NKV_ + kvh) * D_;
    const unsigned short* vbase = Vt + ((size_t)(b * NKV_ + kvh) * D_) * S_;

#define STAGE_KV(buf, kv0) {                                                   \
    _Pragma("unroll")                                                          \
    for (int it = 0; it < 4; ++it) {                                           \
        int row = it * 16 + krb;                                               \
        int cc = ksl ^ (row & 7);                                              \
        gll16(kbase + (size_t)(kv0 + row) * NKV_ * D_ + cc * 8,                \
              &Ksm[buf][(it * 256 + tid) * 8]);                                \
    }                                                                          \
    _Pragma("unroll")                                                          \
    for (int it = 0; it < 4; ++it) {                                           \
        int row = it * 32 + vrb;                                               \
        int cc = vsl ^ (row & 7);                                              \
        gll16(vbase + (size_t)row * S_ + (kv0) + cc * 8,                       \
              &Vsm[buf][(it * 256 + tid) * 8]);                                \
    }                                                                          \
}
#define SB0() __builtin_amdgcn_sched_barrier(0)

    STAGE_KV(0, 0);
    int cur = 0;
    const int ntiles = (qb + 128) >> 6;
    for (int t = 0; t < ntiles; ++t) {
        const int kv0 = t << 6;
        const bool pre = (t + 1 < ntiles);
        if (pre) STAGE_KV(cur ^ 1, kv0 + 64);
        if (pre) { asm volatile("s_waitcnt vmcnt(8)" ::: "memory"); }
        else     { asm volatile("s_waitcnt vmcnt(0)" ::: "memory"); }
        SB0(); __builtin_amdgcn_s_barrier(); SB0();

        if (kv0 < qw0 + 32) {  // wave-uniform causal skip
            // ---- QK^T swapped: sacc[nk][mq]
            f32x4 sacc[4][2];
#pragma unroll
            for (int nk = 0; nk < 4; ++nk)
#pragma unroll
                for (int mq = 0; mq < 2; ++mq) sacc[nk][mq] = f32x4{0.f, 0.f, 0.f, 0.f};
#pragma unroll
            for (int kc = 0; kc < 4; ++kc) {
#pragma unroll
                for (int nk = 0; nk < 4; ++nk) {
                    int row = nk * 16 + la;
                    int slot = (kc * 4 + lb) ^ (la & 7);
                    bf16x8 fk = *(const bf16x8*)&Ksm[cur][row * 128 + slot * 8];
#pragma unroll
                    for (int mq = 0; mq < 2; ++mq)
                        sacc[nk][mq] = mfma16(fk, fq[mq][kc], sacc[nk][mq]);
                }
            }
            // ---- mask + row max
            const bool diag = (kv0 + 63 > qw0);
            float pv[4][2][4];
            float pm[2];
#pragma unroll
            for (int mq = 0; mq < 2; ++mq) {
                int q = qw0 + mq * 16 + la;
                float mx = -__builtin_inff();
#pragma unroll
                for (int nk = 0; nk < 4; ++nk)
#pragma unroll
                    for (int r = 0; r < 4; ++r) {
                        float s = sacc[nk][mq][r];
                        if (diag) {
                            int k = kv0 + nk * 16 + lb * 4 + r;
                            s = (k <= q) ? s : -__builtin_inff();
                        }
                        pv[nk][mq][r] = s;
                        mx = fmaxf(mx, s);
                    }
                mx = fmaxf(mx, __shfl_xor(mx, 16));
                mx = fmaxf(mx, __shfl_xor(mx, 32));
                pm[mq] = mx;
            }
            // T13 defer-rescale (log2 domain, THR=8)
            const bool upd =
                __any((pm[0] > m_[0] + 8.f) || (pm[1] > m_[1] + 8.f));
            if (upd) {
#pragma unroll
                for (int mq = 0; mq < 2; ++mq) {
                    float mn = fmaxf(m_[mq], pm[mq]);
                    float fac = exp2f(m_[mq] - mn);
                    m_[mq] = mn;
                    l_[mq] *= fac;
#pragma unroll
                    for (int db = 0; db < 8; ++db) oacc[db][mq] *= fac;
                }
            }
            float tsum[2] = {0.f, 0.f};
#pragma unroll
            for (int nk = 0; nk < 4; ++nk)
#pragma unroll
                for (int mq = 0; mq < 2; ++mq)
#pragma unroll
                    for (int r = 0; r < 4; ++r) {
                        float p = exp2f(pv[nk][mq][r] - m_[mq]);
                        pv[nk][mq][r] = p;
                        tsum[mq] += p;
                    }
#pragma unroll
            for (int mq = 0; mq < 2; ++mq) {
                float s = tsum[mq];
                s += __shfl_xor(s, 16);
                s += __shfl_xor(s, 32);
                l_[mq] += s;
            }
            // ---- P fragments in-register (hw cvt_pk via __float22bfloat162_rn)
            union { bf16x8 v; __hip_bfloat162 h[4]; } fp[2][2];
#pragma unroll
            for (int mq = 0; mq < 2; ++mq)
#pragma unroll
                for (int ks = 0; ks < 2; ++ks) {
                    fp[mq][ks].h[0] = __float22bfloat162_rn(
                        float2{pv[2 * ks][mq][0], pv[2 * ks][mq][1]});
                    fp[mq][ks].h[1] = __float22bfloat162_rn(
                        float2{pv[2 * ks][mq][2], pv[2 * ks][mq][3]});
                    fp[mq][ks].h[2] = __float22bfloat162_rn(
                        float2{pv[2 * ks + 1][mq][0], pv[2 * ks + 1][mq][1]});
                    fp[mq][ks].h[3] = __float22bfloat162_rn(
                        float2{pv[2 * ks + 1][mq][2], pv[2 * ks + 1][mq][3]});
                }
            // ---- PV: fv via 2x b64 (sigma-permuted cols), O^T += V*P
            const int lbh = lb >> 1, lbo = (lb & 1) * 4;
#pragma unroll
            for (int ks = 0; ks < 2; ++ks)
#pragma unroll
                for (int db = 0; db < 8; ++db) {
                    int row = db * 16 + la;
                    int rx = row & 7;
                    const unsigned short* vb = &Vsm[cur][row * 64];
                    s16x4 v0 = *(const s16x4*)&vb[((ks * 4 + lbh) ^ rx) * 8 + lbo];
                    s16x4 v1 = *(const s16x4*)&vb[((ks * 4 + 2 + lbh) ^ rx) * 8 + lbo];
                    bf16x8 fv = __builtin_shufflevector(v0, v1, 0, 1, 2, 3, 4, 5, 6, 7);
#pragma unroll
                    for (int mq = 0; mq < 2; ++mq)
                        oacc[db][mq] = mfma16(fv, fp[mq][ks].v, oacc[db][mq]);
                }
        }
        SB0(); __builtin_amdgcn_s_barrier(); SB0();
        cur ^= 1;
    }
#undef STAGE_KV
#undef SB0

    // ---- normalize + store: d = db*16+lb*4+r, q = mq*16+la
#pragma unroll
    for (int mq = 0; mq < 2; ++mq) {
        float rl = 1.f / l_[mq];
        int q = qw0 + mq * 16 + la;
#pragma unroll
        for (int db = 0; db < 8; ++db) {
            f32x4 o = oacc[db][mq];
            s16x4 pk;
#pragma unroll
            for (int r = 0; r < 4; ++r) pk[r] = (short)f2bf(o[r] * rl);
            int d = db * 16 + lb * 4;
            *(s16x4*)(Ow + (size_t)(b * S_ + q) * (NH_ * D_) + h * D_ + d) = pk;
        }
    }
}

extern "C" void kernel_launch(void* const* d_in, const int* in_sizes, int n_in,
                              void* d_out, int out_size, void* d_ws, size_t ws_size,
                              hipStream_t stream) {
    const float* hs   = (const float*)d_in[0];
    const float* cosT = (const float*)d_in[1];
    const float* sinT = (const float*)d_in[2];
    const float* Wq   = (const float*)d_in[3];
    const float* Wk   = (const float*)d_in[4];
    const float* Wv   = (const float*)d_in[5];
    const float* Wo   = (const float*)d_in[6];

    constexpr size_t Qn  = (size_t)B_ * S_ * NH_ * D_;    // 16.77M
    constexpr size_t Kn  = (size_t)B_ * S_ * NKV_ * D_;   // 4.19M
    constexpr size_t Hn  = (size_t)B_ * S_ * HID_;        // 16.77M
    constexpr size_t Wqn = (size_t)NH_ * D_ * HID_;       // 16.77M
    constexpr size_t Wkn = (size_t)NKV_ * D_ * HID_;      // 4.19M

    unsigned short* Qws   = (unsigned short*)d_ws;
    unsigned short* Kws   = Qws + Qn;
    unsigned short* Vtws  = Kws + Kn;
    unsigned short* AOws  = Vtws + Kn;
    unsigned short* hsb   = AOws + Qn;
    unsigned short* Wqkvb = hsb + Hn;                  // stacked (6144, 4096)
    unsigned short* Wob   = Wqkvb + Wqn + 2 * Wkn;
    constexpr size_t need = (Qn + 2 * Kn + Qn + Hn + Wqn + 2 * Wkn + Wqn) * 2;

    const int M = B_ * S_;
    dim3 blk(256);

    if (ws_size >= need) {
        // one merged cast launch: hs, Wq, Wk, Wv, Wo -> bf16
        cast_all_k<<<dim3(28672), blk, 0, stream>>>(
            hs, Wq, Wk, Wv, Wo,
            hsb, Wqkvb, Wqkvb + Wqn, Wqkvb + Wqn + Wkn, Wob);

        // Q = rope(hs @ Wq^T) * QSCALE  (grid 16x16 = 256, balanced)
        gemm256_k<1><<<dim3((M / 256) * (HID_ / 256)), dim3(512), 0, stream>>>(
            hsb, Wqkvb, nullptr, Qws, cosT, sinT, M, HID_, HID_);
        // K = rope(hs @ Wk^T), V^T = (hs @ Wv^T)^T  (grid 32x16 = 512 = 2/CU)
        gemm_kv_k<<<dim3((M / 128) * (2048 / 128)), dim3(512), 0, stream>>>(
            hsb, Wqkvb + Wqn, Kws, Vtws, cosT, sinT, M, HID_);
        attn3_k<<<dim3(B_ * NH_ * (S_ / 128)), blk, 0, stream>>>(Qws, Kws, Vtws, AOws);
        // out = AO @ Wo^T (f32 epilogue)
        gemm256_k<0><<<dim3((M / 256) * (HID_ / 256)), dim3(512), 0, stream>>>(
            AOws, Wob, (float*)d_out, nullptr, nullptr, nullptr, M, HID_, NH_ * D_);
    } else {
        // fallback: fp32-staging GEMMs + attention
        unsigned short* Qf = (unsigned short*)d_ws;
        unsigned short* Kf = Qf + Qn;
        unsigned short* Vf = Kf + Kn;
        unsigned short* AOf = Vf + Kn;
        gemm_legacy_k<1, false><<<dim3((M / 128) * (NH_ * D_ / 128)), blk, 0, stream>>>(
            hs, Wq, Qf, cosT, sinT, M, NH_ * D_, HID_, QSCALE_);
        gemm_legacy_k<1, false><<<dim3((M / 128) * (NKV_ * D_ / 128)), blk, 0, stream>>>(
            hs, Wk, Kf, cosT, sinT, M, NKV_ * D_, HID_, 1.0f);
        gemm_legacy_k<3, false><<<dim3((M / 128) * (NKV_ * D_ / 128)), blk, 0, stream>>>(
            hs, Wv, Vf, nullptr, nullptr, M, NKV_ * D_, HID_, 0.f);
        attn3_k<<<dim3(B_ * NH_ * (S_ / 128)), blk, 0, stream>>>(Qf, Kf, Vf, AOf);
        gemm_legacy_k<0, true><<<dim3((M / 128) * (HID_ / 128)), blk, 0, stream>>>(
            AOf, Wo, (float*)d_out, nullptr, nullptr, M, HID_, NH_ * D_, 0.f);
    }
}